// Round 11
// baseline (414.638 us; speedup 1.0000x reference)
//
#include <hip/hip_runtime.h>
#include <hip/hip_bf16.h>

typedef unsigned long long u64;
typedef unsigned int u32;
typedef unsigned short u16;

#define NN   512
#define DIMF 64
#define E2   260
#define KPAD 272
#define MD   17
#define MH   68
#define NH1  128
#define K0   460
#define K1   358
#define K2   307
#define KT   1125
#define O1   460
#define O2   818
#define PADU 1152
#define AS   272
// 64-sender tiles per receiver, one wave each (2 MFMA acc sets of 32)
#define NT0  8
#define NT1  6
#define NT2  5
#define T0T   (K0*NT0)          // 3680
#define T01T  (T0T + K1*NT1)    // 5828
#define TTOT  (T01T + K2*NT2)   // 7363
#define PBLK  ((TTOT+3)/4)      // 1841
#define MSTR  40                // u16 stride of m-repack rows (80 B: conflict-free, R6-proven)
#define WVLDS 5120              // per-wave LDS scratch bytes

typedef __attribute__((ext_vector_type(8)))  short short8;
typedef __attribute__((ext_vector_type(16))) float f32x16;

union SF  { int4 i4; u16 us[8]; u32 w[4]; short8 v; };
union F4U { float4 v; float2 h[2]; float f[4]; u32 w[4]; };

__device__ __forceinline__ float fast_exp2(float x){
#if __has_builtin(__builtin_amdgcn_exp2f)
    return __builtin_amdgcn_exp2f(x);
#else
    return __expf(x * 0.6931471805599453f);
#endif
}
__device__ __forceinline__ float fast_rcp(float x){
#if __has_builtin(__builtin_amdgcn_rcpf)
    return __builtin_amdgcn_rcpf(x);
#else
    return __fdividef(1.0f, x);
#endif
}
__device__ __forceinline__ float siluf(float x){
    return x * fast_rcp(1.0f + fast_exp2(x * -1.4426950408889634f));
}
__device__ __forceinline__ float sigf(float x){
    return fast_rcp(1.0f + fast_exp2(x * -1.4426950408889634f));
}
__device__ __forceinline__ u16 bf16_rne(float f){
    u32 u = __float_as_uint(f);
    u += 0x7FFFu + ((u >> 16) & 1u);
    return (u16)(u >> 16);
}
__device__ __forceinline__ float bf16f(u16 h){
    return __uint_as_float(((u32)h) << 16);
}
__device__ __forceinline__ void lgkm_wait(){
#if __has_builtin(__builtin_amdgcn_s_waitcnt)
    __builtin_amdgcn_s_waitcnt(0xC07F);   // lgkmcnt(0)
#endif
}
// packed float2 helpers (SLP-friendly -> v_pk_fma_f32 / v_pk_add_f32 / v_pk_mul_f32)
__device__ __forceinline__ float2 f2add(float2 a, float2 b){ return float2{a.x+b.x, a.y+b.y}; }
__device__ __forceinline__ float2 f2mul(float2 a, float2 b){ return float2{a.x*b.x, a.y*b.y}; }
__device__ __forceinline__ float2 f2fma(float2 a, float2 b, float2 c){
    return float2{fmaf(a.x,b.x,c.x), fmaf(a.y,b.y,c.y)};
}
__device__ __forceinline__ float2 silu2(float2 p){
    float2 t = f2mul(p, float2{-1.4426950408889634f, -1.4426950408889634f});
    float ex = fast_exp2(t.x), ey = fast_exp2(t.y);
    float rx = fast_rcp(1.0f + ex), ry = fast_rcp(1.0f + ey);
    return float2{p.x*rx, p.y*ry};
}
// truncation-split bf16 pack: hi = upper16(s) via v_perm, lo = s - trunc(s) (then trunc)
__device__ __forceinline__ void pack2(float2 s, u32& hpk, u32& lpk){
    u32 bx = __float_as_uint(s.x), by = __float_as_uint(s.y);
    hpk = __builtin_amdgcn_perm(by, bx, 0x07060302u);
    float lx = s.x - __uint_as_float(bx & 0xFFFF0000u);
    float ly = s.y - __uint_as_float(by & 0xFFFF0000u);
    lpk = __builtin_amdgcn_perm(__float_as_uint(ly), __float_as_uint(lx), 0x07060302u);
}

// ============ fused prep: ug bitmasks + pooling scores + weight fragments ===
__global__ __launch_bounds__(256) void k_pre(
    const float* __restrict__ edge, const float* __restrict__ feat,
    const float* __restrict__ wp, const float* __restrict__ bp,
    const float* __restrict__ We2, const float* __restrict__ Wc1,
    const float* __restrict__ We1, const float* __restrict__ be2,
    const float* __restrict__ bc1, const float* __restrict__ Wc2,
    u64* __restrict__ ugw, float* __restrict__ scores,
    u16* __restrict__ W2f, u16* __restrict__ Wc1f,
    float* __restrict__ wdP, float* __restrict__ weP, float* __restrict__ be2P,
    float* __restrict__ bc1P, float* __restrict__ Wc2P, u64* __restrict__ ug2w){
    int blk = blockIdx.x, t = threadIdx.x;
    if (blk < 128){                      // ug row bitmasks, 4 rows/block
        int i = blk*4 + (t>>6); int lane = t&63;
        const float* row = edge + (size_t)i*NN;
        for (int w = 0; w < 8; w++){
            u64 m = __ballot(row[w*64+lane] != 0.0f);
            if (lane == 0) ugw[i*8+w] = m;
        }
        return;
    }
    if (blk < 134){                      // pooling scores
        int gid = (blk-128)*256 + t; if (gid >= 3*NN) return;
        int l = gid>>9, n = gid&511;
        float s = bp[l];
        for (int d = 0; d < DIMF; d++) s = fmaf(feat[n*DIMF+d], wp[l*DIMF+d], s);
        scores[gid] = sigf(s);
        return;
    }
    int idx = (blk-134)*256 + t;
    if (idx < 52224){                    // We2 frags interleaved hi/lo: [jl][c17][hl2][lane][8]
        int e = idx&7, lane = (idx>>3)&63, hl = (idx>>9)&1, c = (idx>>10)%17, jl = idx/17408;
        int q = lane>>5, nn = lane&31;
        int k = c*16 + q*8 + e;
        float v = (k < E2 && nn < MD) ? We2[jl*E2*MD + k*MD + nn] : 0.0f;
        u16 hi = bf16_rne(v);
        W2f[idx] = hl ? bf16_rne(v - bf16f(hi)) : hi;
        return;
    }
    idx -= 52224;
    if (idx < 9216){                     // Wc1 frags: [jl][T3][c2][lane][8]
        int e = idx & 7, lane = (idx>>3)&63, c2 = (idx>>9)&1, T = (idx>>10)%3, jl = idx/3072;
        int q = lane>>5, nn = lane&31;
        int o = c2*16 + q*8 + e, h = T*32 + nn;
        float v = (o < MD && h < MH) ? Wc1[jl*MD*MH + o*MH + h] : 0.0f;
        Wc1f[idx] = bf16_rne(v);
        return;
    }
    idx -= 9216;
    if (idx < 816){ int jl = idx/KPAD, k = idx%KPAD;
        wdP[idx] = (k < E2) ? We1[jl*130*E2 + 128*E2 + k] : 0.0f; return; }
    idx -= 816;
    if (idx < 816){ int jl = idx/KPAD, k = idx%KPAD;
        weP[idx] = (k < E2) ? We1[jl*130*E2 + 129*E2 + k] : 0.0f; return; }
    idx -= 816;
    if (idx < 96){ int jl = idx/32, o = idx%32;
        be2P[idx] = (o < MD) ? be2[jl*MD+o] : 0.0f; return; }
    idx -= 96;
    if (idx < 288){ int jl = idx/96, h = idx%96;
        bc1P[idx] = (h < MH) ? bc1[jl*MH+h] : 0.0f; return; }
    idx -= 288;
    if (idx < 288){ int jl = idx/96, h = idx%96;
        Wc2P[idx] = (h < MH) ? Wc2[jl*MH+h] : 0.0f; return; }
    idx -= 288;
    if (idx < 4096){ ug2w[idx] = 0ULL; return; }   // zero for k_sortug2's atomicOr
}

// ============ fused: bitonic sort (3 blocks) + ug2 bitset matmul (64 blocks) =
__global__ __launch_bounds__(512) void k_sortug2(
    const float* __restrict__ scores, const u64* __restrict__ ugw,
    float* __restrict__ svals, int* __restrict__ sidx, int* __restrict__ rev,
    u64* __restrict__ ug2w){
    int blk = blockIdx.x, t = threadIdx.x;
    if (blk < 3){
        int l = blk;
        __shared__ float sk[NN];
        __shared__ int   si[NN];
        sk[t] = scores[l*NN+t]; si[t] = t; rev[l*NN+t] = -1;
        __syncthreads();
        for (int k = 2; k <= NN; k <<= 1){
            for (int jj = k>>1; jj > 0; jj >>= 1){
                int p = t ^ jj;
                if (p > t){
                    float ka = sk[t], kb = sk[p];
                    int ia = si[t], ib = si[p];
                    bool before = (ka > kb) || (ka == kb && ia < ib);
                    bool sw = ((t & k) == 0) ? (!before) : before;
                    if (sw){ sk[t]=kb; sk[p]=ka; si[t]=ib; si[p]=ia; }
                }
                __syncthreads();
            }
        }
        svals[l*NN+t] = sk[t]; sidx[l*NN+t] = si[t];
        int kcnt = (l==0)?K0:(l==1)?K1:K2;
        if (t < kcnt) rev[l*NN + si[t]] = t;
    } else {
        // (i, w, kc): row i, out-word w, row-mask word kc. Iterate SET BITS only.
        int gid = (blk-3)*512 + t;       // 32768 total
        int i  = gid >> 6;
        int w  = (gid >> 3) & 7;
        int kc = gid & 7;
        u64 rm = ugw[i*8 + kc];
        u64 acc = 0;
        int base = kc*64;
        while (rm){
            int k2 = __builtin_ctzll(rm);
            rm &= rm - 1;
            acc |= ugw[(base + k2)*8 + w];
        }
        if (acc) atomicOr(&ug2w[i*8 + w], acc);
    }
}

// ============ A/B precompute ================================================
// A row-major per node (zero-padded k 260..271); B in BF[k>>3][u][k&7] groups.
// d-loop unrolled x4 so the compiler batches 8 float4 loads in flight
// (k_gab/k_nodeab run at ~1 block/CU -> load batching is the latency lever).
__device__ __forceinline__ void ab_comp(int jl, const float* __restrict__ We1,
                                        const float* __restrict__ be1, float hval,
                                        int u, int lane,
                                        float* __restrict__ Ap, float* __restrict__ BF){
    const float* W = We1 + jl*130*E2;
    int r  = 4*lane;
    int rt = 256 + lane;
    int rtc = (lane < 4) ? rt : 256;
    F4U av; av.v = *(const float4*)(be1 + jl*E2 + r);
    F4U bv; bv.f[0]=bv.f[1]=bv.f[2]=bv.f[3]=0.0f;
    float avx = be1[jl*E2 + rtc];
    float bvx = 0.0f;
#pragma unroll 4
    for (int d = 0; d < DIMF; d++){
        float hv = __shfl(hval, d);
        F4U w1; w1.v = *(const float4*)(W + d*E2 + r);
        F4U w2; w2.v = *(const float4*)(W + (DIMF+d)*E2 + r);
#pragma unroll
        for (int i = 0; i < 4; i++){
            av.f[i] = fmaf(hv, w1.f[i], av.f[i]);
            bv.f[i] = fmaf(hv, w2.f[i], bv.f[i]);
        }
        avx = fmaf(hv, W[d*E2 + rtc], avx);
        bvx = fmaf(hv, W[(DIMF+d)*E2 + rtc], bvx);
    }
    *(float4*)(Ap + u*AS + r) = av.v;
    *(float4*)(BF + ((size_t)(lane>>1)*PADU + u)*8 + (lane&1)*4) = bv.v;
    if (lane < 16){                     // k = 256..271; zero-pad beyond 259
        int k = 256 + lane;
        float aval = (lane < 4) ? avx : 0.0f;
        float bval = (lane < 4) ? bvx : 0.0f;
        Ap[u*AS + k] = aval;
        BF[((size_t)(k>>3)*PADU + u)*8 + (k&7)] = bval;
    }
}

// ============ gather + AB(layer0) + init mi/c0/c1 ===========================
__global__ __launch_bounds__(256) void k_gab(
    const float* __restrict__ feat, const float* __restrict__ coor,
    const float* __restrict__ svals, const int* __restrict__ sidx,
    const float* __restrict__ We1, const float* __restrict__ be1,
    float* __restrict__ hc, float* __restrict__ c0, float* __restrict__ c1,
    float* __restrict__ mi, float* __restrict__ Ap, float* __restrict__ BF){
    int t = threadIdx.x; int u = blockIdx.x*4 + (t>>6); if (u >= KT) return;
    int lane = t&63;
    int l = (u<K0)?0:(u<O2)?1:2;
    int a = u - ((l==0)?0:(l==1)?O1:O2);
    int org = sidx[l*NN+a];
    float val = svals[l*NN+a];
    float hval = feat[org*DIMF+lane]*val;
    hc[u*DIMF+lane] = hval;
    if (lane < 3){ float c = coor[org*3+lane]; c0[u*4+lane]=c; c1[u*4+lane]=c; }
    if (lane == 3){ c0[u*4+3]=0.0f; c1[u*4+3]=0.0f; }
    if (lane < 20) mi[u*20+lane] = 0.0f;
    ab_comp(0, We1, be1, hval, u, lane, Ap, BF);
}

// ============ per-pair edge MLP via MFMA =====================================
// wave = (receiver u, 64-sender tile): two 32-pair MFMA acc sets. Lane owns
// pairs (tile*64+n) and (+32), k-slice c*16+q*8+e. Software-pipelined global
// loads; A/wd/we via LDS; float2-packed pre/silu; truncation-split bf16 pack
// via v_perm. 3-term bf16-split GEMM into 32x32x16 MFMA.
// launch_bounds(256,4): PROVEN optimum. Loop needs ~96 unified regs (64 VGPR
// + 32 AGPR); (256,5)=102-budget still spilled (R10: 42 MB scratch writes,
// VGPR squeezed to 48); (256,6)=85 spilled worse (R8). Declared min-waves is
// an allocator floor, not a residency cap - HW already runs 5 blocks/CU here.
template<int DOCW>
__global__ __launch_bounds__(256, 4) void k_pair(
    int jl,
    const float* __restrict__ Ap, const float* __restrict__ BF,
    const u16* __restrict__ W2f, const u16* __restrict__ Wc1f,
    const float* __restrict__ wdP, const float* __restrict__ weP,
    const float* __restrict__ be2P, const float* __restrict__ bc1P,
    const float* __restrict__ Wc2P, const float* __restrict__ bc2,
    const float* __restrict__ cin, float* __restrict__ cout,
    float* __restrict__ mi, const int* __restrict__ sidx,
    const u64* __restrict__ ug2w){
    __shared__ __align__(16) char sWK[4*WVLDS];
    __shared__ __align__(16) char sWD[1088];
    __shared__ __align__(16) char sWE[1088];
    int t = threadIdx.x;
    if (t < 68)       ((float4*)sWD)[t]    = *(const float4*)(wdP + jl*KPAD + 4*t);
    else if (t < 136) ((float4*)sWE)[t-68] = *(const float4*)(weP + jl*KPAD + 4*(t-68));
    int wid0 = blockIdx.x*4 + (t>>6);
    int lane = t&63, n = lane&31, q = lane>>5;
    bool dead = (wid0 >= TTOT);
    int wid = dead ? (TTOT-1) : wid0;
    int l, kl, off, a, tile;
    if (wid < T0T)       { l=0; kl=K0; off=0;  a = wid>>3; tile = wid&7; }
    else if (wid < T01T) { int w = wid-T0T;  l=1; kl=K1; off=O1; a = w/NT1; tile = w - a*NT1; }
    else                 { int w = wid-T01T; l=2; kl=K2; off=O2; a = w/NT2; tile = w - a*NT2; }
    int u = off + a;
    int b0 = tile*64 + n, b1 = b0 + 32;
    float act0 = (b0 < kl) ? 1.0f : 0.0f;
    float act1 = (b1 < kl) ? 1.0f : 0.0f;
    int b0c = min(b0, kl-1), b1c = min(b1, kl-1);
    int ub0 = off + b0c, ub1 = off + b1c;
    int ia  = sidx[l*NN+a];
    int ib0 = sidx[l*NN+b0c], ib1 = sidx[l*NN+b1c];
    float ef0 = act0 * (float)((ug2w[ia*8 + (ib0>>6)] >> (ib0&63)) & 1ULL);
    float ef1 = act1 * (float)((ug2w[ia*8 + (ib1>>6)] >> (ib1&63)) & 1ULL);
    F4U ca;  ca.v  = ((const float4*)cin)[u];
    F4U cb0; cb0.v = ((const float4*)cin)[ub0];
    F4U cb1; cb1.v = ((const float4*)cin)[ub1];
    float tx0 = ca.f[0]-cb0.f[0], ty0 = ca.f[1]-cb0.f[1], tz0 = ca.f[2]-cb0.f[2];
    float tx1 = ca.f[0]-cb1.f[0], ty1 = ca.f[1]-cb1.f[1], tz1 = ca.f[2]-cb1.f[2];
    float dd0 = tx0*tx0 + ty0*ty0 + tz0*tz0;
    float dd1 = tx1*tx1 + ty1*ty1 + tz1*tz1;

    char* myk = sWK + (t>>6)*WVLDS;
    {   // stage A for this wave's receiver
        const float* Au = Ap + u*AS;
        ((float4*)myk)[lane] = *(const float4*)(Au + 4*lane);
        if (lane < 4) ((float4*)myk)[64+lane] = *(const float4*)(Au + 256 + 4*lane);
    }
    __syncthreads();

    const float* pB0 = BF + ((size_t)q*PADU + ub0)*8;
    const float* pB1 = BF + ((size_t)q*PADU + ub1)*8;
    const u16*   pW  = W2f + jl*17408 + lane*8;
    const char*  pA  = myk + q*32;
    const char*  pWD = sWD + q*32;
    const char*  pWE = sWE + q*32;

    f32x16 acc0, acc1;
#pragma unroll
    for (int r = 0; r < 16; r++){ acc0[r] = 0.0f; acc1[r] = 0.0f; }

    // prologue loads for c=0
    F4U nb0a, nb0b, nb1a, nb1b; SF nwh, nwl;
    nb0a.v = *(const float4*)(pB0);     nb0b.v = *(const float4*)(pB0 + 4);
    nb1a.v = *(const float4*)(pB1);     nb1b.v = *(const float4*)(pB1 + 4);
    nwh.i4 = *(const int4*)(pW);        nwl.i4 = *(const int4*)(pW + 512);

    float2 DD0{dd0,dd0}, EF0{ef0,ef0}, DD1{dd1,dd1}, EF1{ef1,ef1};

    for (int c = 0; c < 17; c++){
        F4U b0a = nb0a, b0b = nb0b, b1a = nb1a, b1b = nb1b;
        SF  wh  = nwh,  wl  = nwl;
        pB0 += 2*PADU*8; pB1 += 2*PADU*8; pW += 1024;
        if (c < 16){   // issue c+1's global loads before computing c
            nb0a.v = *(const float4*)(pB0);     nb0b.v = *(const float4*)(pB0 + 4);
            nb1a.v = *(const float4*)(pB1);     nb1b.v = *(const float4*)(pB1 + 4);
            nwh.i4 = *(const int4*)(pW);        nwl.i4 = *(const int4*)(pW + 512);
        }
        F4U a0, a1, w0, w1, e0, e1;
        a0.v = *(const float4*)(pA);       a1.v = *(const float4*)(pA + 16);
        w0.v = *(const float4*)(pWD);      w1.v = *(const float4*)(pWD + 16);
        e0.v = *(const float4*)(pWE);      e1.v = *(const float4*)(pWE + 16);
        pA += 64; pWD += 64; pWE += 64;

        SF shi0, slo0, shi1, slo1;
#pragma unroll
        for (int h = 0; h < 2; h++){
            // b0, k-elems 2h..2h+1 (a0 half h) and 4+2h..5+2h (a1 half h)
            float2 p00 = f2fma(EF0, e0.h[h], f2fma(DD0, w0.h[h], f2add(a0.h[h], b0a.h[h])));
            float2 p01 = f2fma(EF0, e1.h[h], f2fma(DD0, w1.h[h], f2add(a1.h[h], b0b.h[h])));
            float2 p10 = f2fma(EF1, e0.h[h], f2fma(DD1, w0.h[h], f2add(a0.h[h], b1a.h[h])));
            float2 p11 = f2fma(EF1, e1.h[h], f2fma(DD1, w1.h[h], f2add(a1.h[h], b1b.h[h])));
            pack2(silu2(p00), shi0.w[h],   slo0.w[h]);
            pack2(silu2(p01), shi0.w[2+h], slo0.w[2+h]);
            pack2(silu2(p10), shi1.w[h],   slo1.w[h]);
            pack2(silu2(p11), shi1.w[2+h], slo1.w[2+h]);
        }
        acc0 = __builtin_amdgcn_mfma_f32_32x32x16_bf16(shi0.v, wh.v, acc0, 0, 0, 0);
        acc0 = __builtin_amdgcn_mfma_f32_32x32x16_bf16(slo0.v, wh.v, acc0, 0, 0, 0);
        acc0 = __builtin_amdgcn_mfma_f32_32x32x16_bf16(shi0.v, wl.v, acc0, 0, 0, 0);
        acc1 = __builtin_amdgcn_mfma_f32_32x32x16_bf16(shi1.v, wh.v, acc1, 0, 0, 0);
        acc1 = __builtin_amdgcn_mfma_f32_32x32x16_bf16(slo1.v, wh.v, acc1, 0, 0, 0);
        acc1 = __builtin_amdgcn_mfma_f32_32x32x16_bf16(shi1.v, wl.v, acc1, 0, 0, 0);
    }

    // ---- m = silu(acc + be2); masked m_i sum; (DOCW) repack to LDS bf16
    float be2v = be2P[jl*32 + n];
    u16* mlds = (u16*)myk;               // overwrites A stage (done with it)
    float msum = 0.0f;
#pragma unroll
    for (int r = 0; r < 16; r++){
        int row = (r&3) + 8*(r>>2) + 4*q;
        float m0 = siluf(acc0[r] + be2v);
        float m1 = siluf(acc1[r] + be2v);
        m0 = (tile*64 + row      < kl) ? m0 : 0.0f;
        m1 = (tile*64 + 32 + row < kl) ? m1 : 0.0f;
        msum += m0 + m1;
        if (DOCW){
            mlds[row*MSTR + n]        = bf16_rne(m0);
            mlds[(row+32)*MSTR + n]   = bf16_rne(m1);
        }
    }
    msum += __shfl_xor(msum, 32);
    if (!dead && lane < MD) atomicAdd(&mi[u*20 + lane], msum);

    if (DOCW){
        lgkm_wait();
        const char* mb = (const char*)mlds;
        float gx = 0.0f, gy = 0.0f, gz = 0.0f;
        float bc2v = bc2[jl];
#pragma unroll
        for (int S = 0; S < 2; S++){
            SF af0, af1;
            af0.i4 = *(const int4*)(mb + (S*32+n)*(MSTR*2) + q*16);
            af1.i4 = *(const int4*)(mb + (S*32+n)*(MSTR*2) + 32 + q*16);
            float cwp[16];
#pragma unroll
            for (int r = 0; r < 16; r++) cwp[r] = 0.0f;
            for (int T = 0; T < 3; T++){
                SF bb0, bb1;
                bb0.i4 = *(const int4*)(Wc1f + jl*3072 + T*1024 +       lane*8);
                bb1.i4 = *(const int4*)(Wc1f + jl*3072 + T*1024 + 512 + lane*8);
                f32x16 p2;
#pragma unroll
                for (int r = 0; r < 16; r++) p2[r] = 0.0f;
                p2 = __builtin_amdgcn_mfma_f32_32x32x16_bf16(af0.v, bb0.v, p2, 0, 0, 0);
                p2 = __builtin_amdgcn_mfma_f32_32x32x16_bf16(af1.v, bb1.v, p2, 0, 0, 0);
                float bc1v = bc1P[jl*96 + T*32 + n];
                float wc2v = Wc2P[jl*96 + T*32 + n];
#pragma unroll
                for (int r = 0; r < 16; r++)
                    cwp[r] = fmaf(siluf(p2[r] + bc1v), wc2v, cwp[r]);
            }
#pragma unroll
            for (int r = 0; r < 16; r++){
                int row  = (r&3) + 8*(r>>2) + 4*q + S*32;
                int brow = tile*64 + row;
                F4U cbr; cbr.v = ((const float4*)cin)[off + min(brow, kl-1)];
                float cw = cwp[r] + ((n == 0) ? bc2v : 0.0f);
                cw = (brow < kl) ? cw : 0.0f;
                gx = fmaf(cw, ca.f[0]-cbr.f[0], gx);
                gy = fmaf(cw, ca.f[1]-cbr.f[1], gy);
                gz = fmaf(cw, ca.f[2]-cbr.f[2], gz);
            }
        }
#pragma unroll
        for (int s = 1; s < 64; s <<= 1){
            gx += __shfl_xor(gx, s); gy += __shfl_xor(gy, s); gz += __shfl_xor(gz, s);
        }
        if (!dead && lane == 0){
            atomicAdd(&cout[u*4+0], gx);
            atomicAdd(&cout[u*4+1], gy);
            atomicAdd(&cout[u*4+2], gz);
        }
    }
}

// ============ node MLP + (optionally) AB for next layer + inits ==============
__global__ __launch_bounds__(256) void k_nodeab(
    int jl, int donext, int docopy,
    const float* __restrict__ Wn1, const float* __restrict__ bn1,
    const float* __restrict__ Wn2, const float* __restrict__ bn2,
    const float* __restrict__ We1, const float* __restrict__ be1,
    float* __restrict__ hc, float* __restrict__ mi,
    const float* __restrict__ ccur, float* __restrict__ cnext,
    float* __restrict__ Ap, float* __restrict__ BF){
    int t = threadIdx.x; int u = blockIdx.x*4 + (t>>6); if (u >= KT) return;
    int lane = t&63;
    float hval = hc[u*DIMF+lane];
    float mval = (lane < MD) ? mi[u*20+lane] : 0.0f;
    const float* W1 = Wn1 + jl*(DIMF+MD)*NH1;
    float v0 = bn1[jl*NH1+lane], v1 = bn1[jl*NH1+lane+64];
#pragma unroll 4
    for (int d = 0; d < DIMF; d++){
        float x = __shfl(hval, d);
        v0 = fmaf(x, W1[d*NH1+lane],    v0);
        v1 = fmaf(x, W1[d*NH1+lane+64], v1);
    }
    for (int d = 0; d < MD; d++){
        float x = __shfl(mval, d);
        v0 = fmaf(x, W1[(DIMF+d)*NH1+lane],    v0);
        v1 = fmaf(x, W1[(DIMF+d)*NH1+lane+64], v1);
    }
    float s0 = siluf(v0), s1 = siluf(v1);
    const float* W2 = Wn2 + jl*NH1*DIMF;
    float h = bn2[jl*DIMF+lane];
#pragma unroll 4
    for (int i = 0; i < 64; i++) h = fmaf(__shfl(s0, i), W2[i*DIMF+lane], h);
#pragma unroll 4
    for (int i = 0; i < 64; i++) h = fmaf(__shfl(s1, i), W2[(64+i)*DIMF+lane], h);
    float hn = fmaxf(0.0f, fmaf(2.0f, hval, h));
    hc[u*DIMF+lane] = hn;
    if (donext){
        if (lane < 20) mi[u*20+lane] = 0.0f;
        if (docopy && lane < 4) cnext[u*4+lane] = ccur[u*4+lane];
        ab_comp(jl+1, We1, be1, hn, u, lane, Ap, BF);
    }
}

// ============ scatter + 3-level max =========================================
__global__ void k_final(const float* __restrict__ hc, const int* __restrict__ rev,
                        float* __restrict__ out){
    int gid = blockIdx.x*blockDim.x + threadIdx.x;
    if (gid >= NN*DIMF) return;
    int nn = gid>>6, d = gid&63;
    float v = 0.0f;
    int a0 = rev[0*NN+nn]; if (a0 >= 0) v = fmaxf(v, hc[(0  + a0)*DIMF + d]);
    int a1 = rev[1*NN+nn]; if (a1 >= 0) v = fmaxf(v, hc[(O1 + a1)*DIMF + d]);
    int a2 = rev[2*NN+nn]; if (a2 >= 0) v = fmaxf(v, hc[(O2 + a2)*DIMF + d]);
    out[gid] = v;
}

extern "C" void kernel_launch(void* const* d_in, const int* in_sizes, int n_in,
                              void* d_out, int out_size, void* d_ws, size_t ws_size,
                              hipStream_t stream) {
    (void)in_sizes; (void)n_in; (void)out_size; (void)ws_size;
    const float* feat = (const float*)d_in[0];
    const float* coor = (const float*)d_in[1];
    const float* edge = (const float*)d_in[2];
    const float* We1  = (const float*)d_in[3];
    const float* be1  = (const float*)d_in[4];
    const float* We2  = (const float*)d_in[5];
    const float* be2  = (const float*)d_in[6];
    const float* Wc1  = (const float*)d_in[7];
    const float* bc1  = (const float*)d_in[8];
    const float* Wc2  = (const float*)d_in[9];
    const float* bc2  = (const float*)d_in[10];
    const float* Wn1  = (const float*)d_in[11];
    const float* bn1  = (const float*)d_in[12];
    const float* Wn2  = (const float*)d_in[13];
    const float* bn2  = (const float*)d_in[14];
    const float* wp   = (const float*)d_in[15];
    const float* bp   = (const float*)d_in[16];
    float* out = (float*)d_out;

    char* wsb = (char*)d_ws;
    u64*   ugw    = (u64*)  (wsb + 0);         // 32768
    u64*   ug2w   = (u64*)  (wsb + 32768);     // 32768
    float* scores = (float*)(wsb + 65536);     // 6144
    float* svals  = (float*)(wsb + 71680);     // 6144
    int*   sidx   = (int*)  (wsb + 77824);     // 6144
    int*   rev    = (int*)  (wsb + 83968);     // 6144
    float* c0     = (float*)(wsb + 90112);     // 18432
    float* c1     = (float*)(wsb + 108544);    // 18432
    float* mi     = (float*)(wsb + 126976);    // 90112
    float* hc     = (float*)(wsb + 217088);    // 288256
    float* Ap     = (float*)(wsb + 505344);    // 1224192
    float* BF     = (float*)(wsb + 1729536);   // 1253376 (34*1152*8*4)
    u16*   W2f    = (u16*)  (wsb + 2982912);   // 104448  (3*17*2*512*2)
    u16*   Wc1f   = (u16*)  (wsb + 3087360);   // 18432
    float* wdP    = (float*)(wsb + 3105792);   // 3328
    float* weP    = (float*)(wsb + 3109120);   // 3328
    float* be2P   = (float*)(wsb + 3112448);   // 384
    float* bc1P   = (float*)(wsb + 3112832);   // 1152
    float* Wc2P   = (float*)(wsb + 3113984);   // 1152  (end ~3.12 MB)

    k_pre<<<399, 256, 0, stream>>>(edge, feat, wp, bp, We2, Wc1, We1, be2, bc1, Wc2,
                                   ugw, scores, W2f, Wc1f,
                                   wdP, weP, be2P, bc1P, Wc2P, ug2w);
    k_sortug2<<<67, 512, 0, stream>>>(scores, ugw, svals, sidx, rev, ug2w);
    k_gab<<<282, 256, 0, stream>>>(feat, coor, svals, sidx, We1, be1,
                                   hc, c0, c1, mi, Ap, BF);
    // layer 0: cin=c0, cout=c1
    k_pair<1><<<PBLK, 256, 0, stream>>>(0, Ap, BF, W2f, Wc1f,
                                        wdP, weP, be2P, bc1P, Wc2P, bc2,
                                        c0, c1, mi, sidx, ug2w);
    k_nodeab<<<282, 256, 0, stream>>>(0, 1, 1, Wn1, bn1, Wn2, bn2, We1, be1,
                                      hc, mi, c1, c0, Ap, BF);
    // layer 1: cin=c1, cout=c0 (pre-initialized to c1 by k_nodeab)
    k_pair<1><<<PBLK, 256, 0, stream>>>(1, Ap, BF, W2f, Wc1f,
                                        wdP, weP, be2P, bc1P, Wc2P, bc2,
                                        c1, c0, mi, sidx, ug2w);
    k_nodeab<<<282, 256, 0, stream>>>(1, 1, 0, Wn1, bn1, Wn2, bn2, We1, be1,
                                      hc, mi, c0, c1, Ap, BF);
    // layer 2: coords output unused -> no coord MLP instantiation
    k_pair<0><<<PBLK, 256, 0, stream>>>(2, Ap, BF, W2f, Wc1f,
                                        wdP, weP, be2P, bc1P, Wc2P, bc2,
                                        c0, c1, mi, sidx, ug2w);
    k_nodeab<<<282, 256, 0, stream>>>(2, 0, 0, Wn1, bn1, Wn2, bn2, We1, be1,
                                      hc, mi, c0, c1, Ap, BF);
    k_final<<<128, 256, 0, stream>>>(hc, rev, out);
}

// Round 12
// 410.057 us; speedup vs baseline: 1.0112x; 1.0112x over previous
//
#include <hip/hip_runtime.h>
#include <hip/hip_bf16.h>

typedef unsigned long long u64;
typedef unsigned int u32;
typedef unsigned short u16;

#define NN   512
#define DIMF 64
#define E2   260
#define KPAD 272
#define MD   17
#define MH   68
#define NH1  128
#define K0   460
#define K1   358
#define K2   307
#define KT   1125
#define O1   460
#define O2   818
#define PADU 1152
#define AS   272
// 64-sender tiles per receiver, one wave each (2 MFMA acc sets of 32)
#define NT0  8
#define NT1  6
#define NT2  5
#define T0T   (K0*NT0)          // 3680
#define T01T  (T0T + K1*NT1)    // 5828
#define TTOT  (T01T + K2*NT2)   // 7363
#define PBLK  ((TTOT+3)/4)      // 1841
#define MSTR  40                // u16 stride of m-repack rows (80 B: conflict-free, R6-proven)
#define WVLDS 5120              // per-wave LDS scratch bytes

typedef __attribute__((ext_vector_type(8)))  short short8;
typedef __attribute__((ext_vector_type(16))) float f32x16;

union SF  { int4 i4; u16 us[8]; u32 w[4]; short8 v; };
union F4U { float4 v; float2 h[2]; float f[4]; u32 w[4]; };

__device__ __forceinline__ float fast_exp2(float x){
#if __has_builtin(__builtin_amdgcn_exp2f)
    return __builtin_amdgcn_exp2f(x);
#else
    return __expf(x * 0.6931471805599453f);
#endif
}
__device__ __forceinline__ float fast_rcp(float x){
#if __has_builtin(__builtin_amdgcn_rcpf)
    return __builtin_amdgcn_rcpf(x);
#else
    return __fdividef(1.0f, x);
#endif
}
__device__ __forceinline__ float siluf(float x){
    return x * fast_rcp(1.0f + fast_exp2(x * -1.4426950408889634f));
}
__device__ __forceinline__ float sigf(float x){
    return fast_rcp(1.0f + fast_exp2(x * -1.4426950408889634f));
}
__device__ __forceinline__ u16 bf16_rne(float f){
    u32 u = __float_as_uint(f);
    u += 0x7FFFu + ((u >> 16) & 1u);
    return (u16)(u >> 16);
}
__device__ __forceinline__ float bf16f(u16 h){
    return __uint_as_float(((u32)h) << 16);
}
__device__ __forceinline__ void lgkm_wait(){
#if __has_builtin(__builtin_amdgcn_s_waitcnt)
    __builtin_amdgcn_s_waitcnt(0xC07F);   // lgkmcnt(0)
#endif
}
// packed float2 helpers (SLP-friendly -> v_pk_fma_f32 / v_pk_add_f32 / v_pk_mul_f32)
__device__ __forceinline__ float2 f2add(float2 a, float2 b){ return float2{a.x+b.x, a.y+b.y}; }
__device__ __forceinline__ float2 f2mul(float2 a, float2 b){ return float2{a.x*b.x, a.y*b.y}; }
__device__ __forceinline__ float2 f2fma(float2 a, float2 b, float2 c){
    return float2{fmaf(a.x,b.x,c.x), fmaf(a.y,b.y,c.y)};
}
__device__ __forceinline__ float2 silu2(float2 p){
    float2 t = f2mul(p, float2{-1.4426950408889634f, -1.4426950408889634f});
    float ex = fast_exp2(t.x), ey = fast_exp2(t.y);
    float rx = fast_rcp(1.0f + ex), ry = fast_rcp(1.0f + ey);
    return float2{p.x*rx, p.y*ry};
}
// truncation-split bf16 pack: hi = upper16(s) via v_perm, lo = s - trunc(s) (then trunc)
__device__ __forceinline__ void pack2(float2 s, u32& hpk, u32& lpk){
    u32 bx = __float_as_uint(s.x), by = __float_as_uint(s.y);
    hpk = __builtin_amdgcn_perm(by, bx, 0x07060302u);
    float lx = s.x - __uint_as_float(bx & 0xFFFF0000u);
    float ly = s.y - __uint_as_float(by & 0xFFFF0000u);
    lpk = __builtin_amdgcn_perm(__float_as_uint(ly), __float_as_uint(lx), 0x07060302u);
}

// ============ fused prep: ug bitmasks + pooling scores + weight fragments ===
__global__ __launch_bounds__(256) void k_pre(
    const float* __restrict__ edge, const float* __restrict__ feat,
    const float* __restrict__ wp, const float* __restrict__ bp,
    const float* __restrict__ We2, const float* __restrict__ Wc1,
    const float* __restrict__ We1, const float* __restrict__ be2,
    const float* __restrict__ bc1, const float* __restrict__ Wc2,
    u64* __restrict__ ugw, float* __restrict__ scores,
    u16* __restrict__ W2f, u16* __restrict__ Wc1f,
    float* __restrict__ wdP, float* __restrict__ weP, float* __restrict__ be2P,
    float* __restrict__ bc1P, float* __restrict__ Wc2P, u64* __restrict__ ug2w){
    int blk = blockIdx.x, t = threadIdx.x;
    if (blk < 128){                      // ug row bitmasks, 4 rows/block
        int i = blk*4 + (t>>6); int lane = t&63;
        const float* row = edge + (size_t)i*NN;
        for (int w = 0; w < 8; w++){
            u64 m = __ballot(row[w*64+lane] != 0.0f);
            if (lane == 0) ugw[i*8+w] = m;
        }
        return;
    }
    if (blk < 134){                      // pooling scores
        int gid = (blk-128)*256 + t; if (gid >= 3*NN) return;
        int l = gid>>9, n = gid&511;
        float s = bp[l];
        for (int d = 0; d < DIMF; d++) s = fmaf(feat[n*DIMF+d], wp[l*DIMF+d], s);
        scores[gid] = sigf(s);
        return;
    }
    int idx = (blk-134)*256 + t;
    if (idx < 52224){                    // We2 frags interleaved hi/lo: [jl][c17][hl2][lane][8]
        int e = idx&7, lane = (idx>>3)&63, hl = (idx>>9)&1, c = (idx>>10)%17, jl = idx/17408;
        int q = lane>>5, nn = lane&31;
        int k = c*16 + q*8 + e;
        float v = (k < E2 && nn < MD) ? We2[jl*E2*MD + k*MD + nn] : 0.0f;
        u16 hi = bf16_rne(v);
        W2f[idx] = hl ? bf16_rne(v - bf16f(hi)) : hi;
        return;
    }
    idx -= 52224;
    if (idx < 9216){                     // Wc1 frags: [jl][T3][c2][lane][8]
        int e = idx & 7, lane = (idx>>3)&63, c2 = (idx>>9)&1, T = (idx>>10)%3, jl = idx/3072;
        int q = lane>>5, nn = lane&31;
        int o = c2*16 + q*8 + e, h = T*32 + nn;
        float v = (o < MD && h < MH) ? Wc1[jl*MD*MH + o*MH + h] : 0.0f;
        Wc1f[idx] = bf16_rne(v);
        return;
    }
    idx -= 9216;
    if (idx < 816){ int jl = idx/KPAD, k = idx%KPAD;
        wdP[idx] = (k < E2) ? We1[jl*130*E2 + 128*E2 + k] : 0.0f; return; }
    idx -= 816;
    if (idx < 816){ int jl = idx/KPAD, k = idx%KPAD;
        weP[idx] = (k < E2) ? We1[jl*130*E2 + 129*E2 + k] : 0.0f; return; }
    idx -= 816;
    if (idx < 96){ int jl = idx/32, o = idx%32;
        be2P[idx] = (o < MD) ? be2[jl*MD+o] : 0.0f; return; }
    idx -= 96;
    if (idx < 288){ int jl = idx/96, h = idx%96;
        bc1P[idx] = (h < MH) ? bc1[jl*MH+h] : 0.0f; return; }
    idx -= 288;
    if (idx < 288){ int jl = idx/96, h = idx%96;
        Wc2P[idx] = (h < MH) ? Wc2[jl*MH+h] : 0.0f; return; }
    idx -= 288;
    if (idx < 4096){ ug2w[idx] = 0ULL; return; }   // zero for k_sortug2's atomicOr
}

// ============ fused: bitonic sort (3 blocks) + ug2 bitset matmul (64 blocks) =
__global__ __launch_bounds__(512) void k_sortug2(
    const float* __restrict__ scores, const u64* __restrict__ ugw,
    float* __restrict__ svals, int* __restrict__ sidx, int* __restrict__ rev,
    u64* __restrict__ ug2w){
    int blk = blockIdx.x, t = threadIdx.x;
    if (blk < 3){
        int l = blk;
        __shared__ float sk[NN];
        __shared__ int   si[NN];
        sk[t] = scores[l*NN+t]; si[t] = t; rev[l*NN+t] = -1;
        __syncthreads();
        for (int k = 2; k <= NN; k <<= 1){
            for (int jj = k>>1; jj > 0; jj >>= 1){
                int p = t ^ jj;
                if (p > t){
                    float ka = sk[t], kb = sk[p];
                    int ia = si[t], ib = si[p];
                    bool before = (ka > kb) || (ka == kb && ia < ib);
                    bool sw = ((t & k) == 0) ? (!before) : before;
                    if (sw){ sk[t]=kb; sk[p]=ka; si[t]=ib; si[p]=ia; }
                }
                __syncthreads();
            }
        }
        svals[l*NN+t] = sk[t]; sidx[l*NN+t] = si[t];
        int kcnt = (l==0)?K0:(l==1)?K1:K2;
        if (t < kcnt) rev[l*NN + si[t]] = t;
    } else {
        // (i, w, kc): row i, out-word w, row-mask word kc. Iterate SET BITS only.
        int gid = (blk-3)*512 + t;       // 32768 total
        int i  = gid >> 6;
        int w  = (gid >> 3) & 7;
        int kc = gid & 7;
        u64 rm = ugw[i*8 + kc];
        u64 acc = 0;
        int base = kc*64;
        while (rm){
            int k2 = __builtin_ctzll(rm);
            rm &= rm - 1;
            acc |= ugw[(base + k2)*8 + w];
        }
        if (acc) atomicOr(&ug2w[i*8 + w], acc);
    }
}

// ============ A/B precompute ================================================
// A row-major per node (zero-padded k 260..271); B in BF[k>>3][u][k&7] groups.
__device__ __forceinline__ void ab_comp(int jl, const float* __restrict__ We1,
                                        const float* __restrict__ be1, float hval,
                                        int u, int lane,
                                        float* __restrict__ Ap, float* __restrict__ BF){
    const float* W = We1 + jl*130*E2;
    int r  = 4*lane;
    int rt = 256 + lane;
    int rtc = (lane < 4) ? rt : 256;
    F4U av; av.v = *(const float4*)(be1 + jl*E2 + r);
    F4U bv; bv.f[0]=bv.f[1]=bv.f[2]=bv.f[3]=0.0f;
    float avx = be1[jl*E2 + rtc];
    float bvx = 0.0f;
    for (int d = 0; d < DIMF; d++){
        float hv = __shfl(hval, d);
        F4U w1; w1.v = *(const float4*)(W + d*E2 + r);
        F4U w2; w2.v = *(const float4*)(W + (DIMF+d)*E2 + r);
#pragma unroll
        for (int i = 0; i < 4; i++){
            av.f[i] = fmaf(hv, w1.f[i], av.f[i]);
            bv.f[i] = fmaf(hv, w2.f[i], bv.f[i]);
        }
        avx = fmaf(hv, W[d*E2 + rtc], avx);
        bvx = fmaf(hv, W[(DIMF+d)*E2 + rtc], bvx);
    }
    *(float4*)(Ap + u*AS + r) = av.v;
    *(float4*)(BF + ((size_t)(lane>>1)*PADU + u)*8 + (lane&1)*4) = bv.v;
    if (lane < 16){                     // k = 256..271; zero-pad beyond 259
        int k = 256 + lane;
        float aval = (lane < 4) ? avx : 0.0f;
        float bval = (lane < 4) ? bvx : 0.0f;
        Ap[u*AS + k] = aval;
        BF[((size_t)(k>>3)*PADU + u)*8 + (k&7)] = bval;
    }
}

// ============ gather + AB(layer0) + init mi/c0/c1 ===========================
__global__ __launch_bounds__(256) void k_gab(
    const float* __restrict__ feat, const float* __restrict__ coor,
    const float* __restrict__ svals, const int* __restrict__ sidx,
    const float* __restrict__ We1, const float* __restrict__ be1,
    float* __restrict__ hc, float* __restrict__ c0, float* __restrict__ c1,
    float* __restrict__ mi, float* __restrict__ Ap, float* __restrict__ BF){
    int t = threadIdx.x; int u = blockIdx.x*4 + (t>>6); if (u >= KT) return;
    int lane = t&63;
    int l = (u<K0)?0:(u<O2)?1:2;
    int a = u - ((l==0)?0:(l==1)?O1:O2);
    int org = sidx[l*NN+a];
    float val = svals[l*NN+a];
    float hval = feat[org*DIMF+lane]*val;
    hc[u*DIMF+lane] = hval;
    if (lane < 3){ float c = coor[org*3+lane]; c0[u*4+lane]=c; c1[u*4+lane]=c; }
    if (lane == 3){ c0[u*4+3]=0.0f; c1[u*4+3]=0.0f; }
    if (lane < 20) mi[u*20+lane] = 0.0f;
    ab_comp(0, We1, be1, hval, u, lane, Ap, BF);
}

// ============ per-pair edge MLP via MFMA =====================================
// wave = (receiver u, 64-sender tile): two 32-pair MFMA acc sets.
// 2-term bf16 split: acc = shi@Whi + slo@Whi == s @ bf16RNE(We2) — the
// shi@Wlo weight-correction term is dropped (equivalent to ~2^-9 unbiased
// weight perturbation; error budget verified R12). Manual ping-pong unroll-2
// (8x2+1) replaces the rotating-register pipeline: no next->cur copies.
// launch_bounds(256,4): PROVEN optimum (R8/R10: any lower budget spills).
template<int DOCW>
__global__ __launch_bounds__(256, 4) void k_pair(
    int jl,
    const float* __restrict__ Ap, const float* __restrict__ BF,
    const u16* __restrict__ W2f, const u16* __restrict__ Wc1f,
    const float* __restrict__ wdP, const float* __restrict__ weP,
    const float* __restrict__ be2P, const float* __restrict__ bc1P,
    const float* __restrict__ Wc2P, const float* __restrict__ bc2,
    const float* __restrict__ cin, float* __restrict__ cout,
    float* __restrict__ mi, const int* __restrict__ sidx,
    const u64* __restrict__ ug2w){
    __shared__ __align__(16) char sWK[4*WVLDS];
    __shared__ __align__(16) char sWD[1088];
    __shared__ __align__(16) char sWE[1088];
    int t = threadIdx.x;
    if (t < 68)       ((float4*)sWD)[t]    = *(const float4*)(wdP + jl*KPAD + 4*t);
    else if (t < 136) ((float4*)sWE)[t-68] = *(const float4*)(weP + jl*KPAD + 4*(t-68));
    int wid0 = blockIdx.x*4 + (t>>6);
    int lane = t&63, n = lane&31, q = lane>>5;
    bool dead = (wid0 >= TTOT);
    int wid = dead ? (TTOT-1) : wid0;
    int l, kl, off, a, tile;
    if (wid < T0T)       { l=0; kl=K0; off=0;  a = wid>>3; tile = wid&7; }
    else if (wid < T01T) { int w = wid-T0T;  l=1; kl=K1; off=O1; a = w/NT1; tile = w - a*NT1; }
    else                 { int w = wid-T01T; l=2; kl=K2; off=O2; a = w/NT2; tile = w - a*NT2; }
    int u = off + a;
    int b0 = tile*64 + n, b1 = b0 + 32;
    float act0 = (b0 < kl) ? 1.0f : 0.0f;
    float act1 = (b1 < kl) ? 1.0f : 0.0f;
    int b0c = min(b0, kl-1), b1c = min(b1, kl-1);
    int ub0 = off + b0c, ub1 = off + b1c;
    int ia  = sidx[l*NN+a];
    int ib0 = sidx[l*NN+b0c], ib1 = sidx[l*NN+b1c];
    float ef0 = act0 * (float)((ug2w[ia*8 + (ib0>>6)] >> (ib0&63)) & 1ULL);
    float ef1 = act1 * (float)((ug2w[ia*8 + (ib1>>6)] >> (ib1&63)) & 1ULL);
    F4U ca;  ca.v  = ((const float4*)cin)[u];
    F4U cb0; cb0.v = ((const float4*)cin)[ub0];
    F4U cb1; cb1.v = ((const float4*)cin)[ub1];
    float tx0 = ca.f[0]-cb0.f[0], ty0 = ca.f[1]-cb0.f[1], tz0 = ca.f[2]-cb0.f[2];
    float tx1 = ca.f[0]-cb1.f[0], ty1 = ca.f[1]-cb1.f[1], tz1 = ca.f[2]-cb1.f[2];
    float dd0 = tx0*tx0 + ty0*ty0 + tz0*tz0;
    float dd1 = tx1*tx1 + ty1*ty1 + tz1*tz1;

    char* myk = sWK + (t>>6)*WVLDS;
    {   // stage A for this wave's receiver
        const float* Au = Ap + u*AS;
        ((float4*)myk)[lane] = *(const float4*)(Au + 4*lane);
        if (lane < 4) ((float4*)myk)[64+lane] = *(const float4*)(Au + 256 + 4*lane);
    }
    __syncthreads();

    const float* pB0 = BF + ((size_t)q*PADU + ub0)*8;
    const float* pB1 = BF + ((size_t)q*PADU + ub1)*8;
    const u16*   pW  = W2f + jl*17408 + lane*8;
    const char*  pA  = myk + q*32;
    const char*  pWD = sWD + q*32;
    const char*  pWE = sWE + q*32;

    f32x16 acc0, acc1;
#pragma unroll
    for (int r = 0; r < 16; r++){ acc0[r] = 0.0f; acc1[r] = 0.0f; }

    float2 DD0{dd0,dd0}, EF0{ef0,ef0}, DD1{dd1,dd1}, EF1{ef1,ef1};

    // ping-pong buffers
    F4U b0aA, b0bA, b1aA, b1bA; SF whA;
    F4U b0aB, b0bB, b1aB, b1bB; SF whB;

    auto loadc = [&](F4U& x0, F4U& x1, F4U& y0, F4U& y1, SF& wh){
        x0.v = *(const float4*)(pB0);  x1.v = *(const float4*)(pB0 + 4);
        y0.v = *(const float4*)(pB1);  y1.v = *(const float4*)(pB1 + 4);
        wh.i4 = *(const int4*)(pW);
        pB0 += 2*PADU*8; pB1 += 2*PADU*8; pW += 1024;
    };
    auto compc = [&](F4U& b0a, F4U& b0b, F4U& b1a, F4U& b1b, SF& wh){
        F4U a0, a1, w0, w1, e0, e1;
        a0.v = *(const float4*)(pA);   a1.v = *(const float4*)(pA + 16);
        w0.v = *(const float4*)(pWD);  w1.v = *(const float4*)(pWD + 16);
        e0.v = *(const float4*)(pWE);  e1.v = *(const float4*)(pWE + 16);
        pA += 64; pWD += 64; pWE += 64;
        SF shi0, slo0, shi1, slo1;
#pragma unroll
        for (int h = 0; h < 2; h++){
            float2 p00 = f2fma(EF0, e0.h[h], f2fma(DD0, w0.h[h], f2add(a0.h[h], b0a.h[h])));
            float2 p01 = f2fma(EF0, e1.h[h], f2fma(DD0, w1.h[h], f2add(a1.h[h], b0b.h[h])));
            float2 p10 = f2fma(EF1, e0.h[h], f2fma(DD1, w0.h[h], f2add(a0.h[h], b1a.h[h])));
            float2 p11 = f2fma(EF1, e1.h[h], f2fma(DD1, w1.h[h], f2add(a1.h[h], b1b.h[h])));
            pack2(silu2(p00), shi0.w[h],   slo0.w[h]);
            pack2(silu2(p01), shi0.w[2+h], slo0.w[2+h]);
            pack2(silu2(p10), shi1.w[h],   slo1.w[h]);
            pack2(silu2(p11), shi1.w[2+h], slo1.w[2+h]);
        }
        acc0 = __builtin_amdgcn_mfma_f32_32x32x16_bf16(shi0.v, wh.v, acc0, 0, 0, 0);
        acc0 = __builtin_amdgcn_mfma_f32_32x32x16_bf16(slo0.v, wh.v, acc0, 0, 0, 0);
        acc1 = __builtin_amdgcn_mfma_f32_32x32x16_bf16(shi1.v, wh.v, acc1, 0, 0, 0);
        acc1 = __builtin_amdgcn_mfma_f32_32x32x16_bf16(slo1.v, wh.v, acc1, 0, 0, 0);
    };

    loadc(b0aA, b0bA, b1aA, b1bA, whA);            // c=0
    for (int cc = 0; cc < 8; cc++){
        loadc(b0aB, b0bB, b1aB, b1bB, whB);        // c=2cc+1
        compc(b0aA, b0bA, b1aA, b1bA, whA);        // c=2cc
        loadc(b0aA, b0bA, b1aA, b1bA, whA);        // c=2cc+2
        compc(b0aB, b0bB, b1aB, b1bB, whB);        // c=2cc+1
    }
    compc(b0aA, b0bA, b1aA, b1bA, whA);            // c=16

    // ---- m = silu(acc + be2); masked m_i sum; (DOCW) repack to LDS bf16
    float be2v = be2P[jl*32 + n];
    u16* mlds = (u16*)myk;               // overwrites A stage (done with it)
    float msum = 0.0f;
#pragma unroll
    for (int r = 0; r < 16; r++){
        int row = (r&3) + 8*(r>>2) + 4*q;
        float m0 = siluf(acc0[r] + be2v);
        float m1 = siluf(acc1[r] + be2v);
        m0 = (tile*64 + row      < kl) ? m0 : 0.0f;
        m1 = (tile*64 + 32 + row < kl) ? m1 : 0.0f;
        msum += m0 + m1;
        if (DOCW){
            mlds[row*MSTR + n]        = bf16_rne(m0);
            mlds[(row+32)*MSTR + n]   = bf16_rne(m1);
        }
    }
    msum += __shfl_xor(msum, 32);
    if (!dead && lane < MD) atomicAdd(&mi[u*20 + lane], msum);

    if (DOCW){
        lgkm_wait();
        const char* mb = (const char*)mlds;
        float gx = 0.0f, gy = 0.0f, gz = 0.0f;
        float bc2v = bc2[jl];
#pragma unroll
        for (int S = 0; S < 2; S++){
            SF af0, af1;
            af0.i4 = *(const int4*)(mb + (S*32+n)*(MSTR*2) + q*16);
            af1.i4 = *(const int4*)(mb + (S*32+n)*(MSTR*2) + 32 + q*16);
            float cwp[16];
#pragma unroll
            for (int r = 0; r < 16; r++) cwp[r] = 0.0f;
            for (int T = 0; T < 3; T++){
                SF bb0, bb1;
                bb0.i4 = *(const int4*)(Wc1f + jl*3072 + T*1024 +       lane*8);
                bb1.i4 = *(const int4*)(Wc1f + jl*3072 + T*1024 + 512 + lane*8);
                f32x16 p2;
#pragma unroll
                for (int r = 0; r < 16; r++) p2[r] = 0.0f;
                p2 = __builtin_amdgcn_mfma_f32_32x32x16_bf16(af0.v, bb0.v, p2, 0, 0, 0);
                p2 = __builtin_amdgcn_mfma_f32_32x32x16_bf16(af1.v, bb1.v, p2, 0, 0, 0);
                float bc1v = bc1P[jl*96 + T*32 + n];
                float wc2v = Wc2P[jl*96 + T*32 + n];
#pragma unroll
                for (int r = 0; r < 16; r++)
                    cwp[r] = fmaf(siluf(p2[r] + bc1v), wc2v, cwp[r]);
            }
#pragma unroll
            for (int r = 0; r < 16; r++){
                int row  = (r&3) + 8*(r>>2) + 4*q + S*32;
                int brow = tile*64 + row;
                F4U cbr; cbr.v = ((const float4*)cin)[off + min(brow, kl-1)];
                float cw = cwp[r] + ((n == 0) ? bc2v : 0.0f);
                cw = (brow < kl) ? cw : 0.0f;
                gx = fmaf(cw, ca.f[0]-cbr.f[0], gx);
                gy = fmaf(cw, ca.f[1]-cbr.f[1], gy);
                gz = fmaf(cw, ca.f[2]-cbr.f[2], gz);
            }
        }
#pragma unroll
        for (int s = 1; s < 64; s <<= 1){
            gx += __shfl_xor(gx, s); gy += __shfl_xor(gy, s); gz += __shfl_xor(gz, s);
        }
        if (!dead && lane == 0){
            atomicAdd(&cout[u*4+0], gx);
            atomicAdd(&cout[u*4+1], gy);
            atomicAdd(&cout[u*4+2], gz);
        }
    }
}

// ============ node MLP + (optionally) AB for next layer + inits ==============
__global__ __launch_bounds__(256) void k_nodeab(
    int jl, int donext, int docopy,
    const float* __restrict__ Wn1, const float* __restrict__ bn1,
    const float* __restrict__ Wn2, const float* __restrict__ bn2,
    const float* __restrict__ We1, const float* __restrict__ be1,
    float* __restrict__ hc, float* __restrict__ mi,
    const float* __restrict__ ccur, float* __restrict__ cnext,
    float* __restrict__ Ap, float* __restrict__ BF){
    int t = threadIdx.x; int u = blockIdx.x*4 + (t>>6); if (u >= KT) return;
    int lane = t&63;
    float hval = hc[u*DIMF+lane];
    float mval = (lane < MD) ? mi[u*20+lane] : 0.0f;
    const float* W1 = Wn1 + jl*(DIMF+MD)*NH1;
    float v0 = bn1[jl*NH1+lane], v1 = bn1[jl*NH1+lane+64];
    for (int d = 0; d < DIMF; d++){
        float x = __shfl(hval, d);
        v0 = fmaf(x, W1[d*NH1+lane],    v0);
        v1 = fmaf(x, W1[d*NH1+lane+64], v1);
    }
    for (int d = 0; d < MD; d++){
        float x = __shfl(mval, d);
        v0 = fmaf(x, W1[(DIMF+d)*NH1+lane],    v0);
        v1 = fmaf(x, W1[(DIMF+d)*NH1+lane+64], v1);
    }
    float s0 = siluf(v0), s1 = siluf(v1);
    const float* W2 = Wn2 + jl*NH1*DIMF;
    float h = bn2[jl*DIMF+lane];
    for (int i = 0; i < 64; i++) h = fmaf(__shfl(s0, i), W2[i*DIMF+lane], h);
    for (int i = 0; i < 64; i++) h = fmaf(__shfl(s1, i), W2[(64+i)*DIMF+lane], h);
    float hn = fmaxf(0.0f, fmaf(2.0f, hval, h));
    hc[u*DIMF+lane] = hn;
    if (donext){
        if (lane < 20) mi[u*20+lane] = 0.0f;
        if (docopy && lane < 4) cnext[u*4+lane] = ccur[u*4+lane];
        ab_comp(jl+1, We1, be1, hn, u, lane, Ap, BF);
    }
}

// ============ scatter + 3-level max =========================================
__global__ void k_final(const float* __restrict__ hc, const int* __restrict__ rev,
                        float* __restrict__ out){
    int gid = blockIdx.x*blockDim.x + threadIdx.x;
    if (gid >= NN*DIMF) return;
    int nn = gid>>6, d = gid&63;
    float v = 0.0f;
    int a0 = rev[0*NN+nn]; if (a0 >= 0) v = fmaxf(v, hc[(0  + a0)*DIMF + d]);
    int a1 = rev[1*NN+nn]; if (a1 >= 0) v = fmaxf(v, hc[(O1 + a1)*DIMF + d]);
    int a2 = rev[2*NN+nn]; if (a2 >= 0) v = fmaxf(v, hc[(O2 + a2)*DIMF + d]);
    out[gid] = v;
}

extern "C" void kernel_launch(void* const* d_in, const int* in_sizes, int n_in,
                              void* d_out, int out_size, void* d_ws, size_t ws_size,
                              hipStream_t stream) {
    (void)in_sizes; (void)n_in; (void)out_size; (void)ws_size;
    const float* feat = (const float*)d_in[0];
    const float* coor = (const float*)d_in[1];
    const float* edge = (const float*)d_in[2];
    const float* We1  = (const float*)d_in[3];
    const float* be1  = (const float*)d_in[4];
    const float* We2  = (const float*)d_in[5];
    const float* be2  = (const float*)d_in[6];
    const float* Wc1  = (const float*)d_in[7];
    const float* bc1  = (const float*)d_in[8];
    const float* Wc2  = (const float*)d_in[9];
    const float* bc2  = (const float*)d_in[10];
    const float* Wn1  = (const float*)d_in[11];
    const float* bn1  = (const float*)d_in[12];
    const float* Wn2  = (const float*)d_in[13];
    const float* bn2  = (const float*)d_in[14];
    const float* wp   = (const float*)d_in[15];
    const float* bp   = (const float*)d_in[16];
    float* out = (float*)d_out;

    char* wsb = (char*)d_ws;
    u64*   ugw    = (u64*)  (wsb + 0);         // 32768
    u64*   ug2w   = (u64*)  (wsb + 32768);     // 32768
    float* scores = (float*)(wsb + 65536);     // 6144
    float* svals  = (float*)(wsb + 71680);     // 6144
    int*   sidx   = (int*)  (wsb + 77824);     // 6144
    int*   rev    = (int*)  (wsb + 83968);     // 6144
    float* c0     = (float*)(wsb + 90112);     // 18432
    float* c1     = (float*)(wsb + 108544);    // 18432
    float* mi     = (float*)(wsb + 126976);    // 90112
    float* hc     = (float*)(wsb + 217088);    // 288256
    float* Ap     = (float*)(wsb + 505344);    // 1224192
    float* BF     = (float*)(wsb + 1729536);   // 1253376 (34*1152*8*4)
    u16*   W2f    = (u16*)  (wsb + 2982912);   // 104448  (3*17*2*512*2)
    u16*   Wc1f   = (u16*)  (wsb + 3087360);   // 18432
    float* wdP    = (float*)(wsb + 3105792);   // 3328
    float* weP    = (float*)(wsb + 3109120);   // 3328
    float* be2P   = (float*)(wsb + 3112448);   // 384
    float* bc1P   = (float*)(wsb + 3112832);   // 1152
    float* Wc2P   = (float*)(wsb + 3113984);   // 1152  (end ~3.12 MB)

    k_pre<<<399, 256, 0, stream>>>(edge, feat, wp, bp, We2, Wc1, We1, be2, bc1, Wc2,
                                   ugw, scores, W2f, Wc1f,
                                   wdP, weP, be2P, bc1P, Wc2P, ug2w);
    k_sortug2<<<67, 512, 0, stream>>>(scores, ugw, svals, sidx, rev, ug2w);
    k_gab<<<282, 256, 0, stream>>>(feat, coor, svals, sidx, We1, be1,
                                   hc, c0, c1, mi, Ap, BF);
    // layer 0: cin=c0, cout=c1
    k_pair<1><<<PBLK, 256, 0, stream>>>(0, Ap, BF, W2f, Wc1f,
                                        wdP, weP, be2P, bc1P, Wc2P, bc2,
                                        c0, c1, mi, sidx, ug2w);
    k_nodeab<<<282, 256, 0, stream>>>(0, 1, 1, Wn1, bn1, Wn2, bn2, We1, be1,
                                      hc, mi, c1, c0, Ap, BF);
    // layer 1: cin=c1, cout=c0 (pre-initialized to c1 by k_nodeab)
    k_pair<1><<<PBLK, 256, 0, stream>>>(1, Ap, BF, W2f, Wc1f,
                                        wdP, weP, be2P, bc1P, Wc2P, bc2,
                                        c1, c0, mi, sidx, ug2w);
    k_nodeab<<<282, 256, 0, stream>>>(1, 1, 0, Wn1, bn1, Wn2, bn2, We1, be1,
                                      hc, mi, c0, c1, Ap, BF);
    // layer 2: coords output unused -> no coord MLP instantiation
    k_pair<0><<<PBLK, 256, 0, stream>>>(2, Ap, BF, W2f, Wc1f,
                                        wdP, weP, be2P, bc1P, Wc2P, bc2,
                                        c0, c1, mi, sidx, ug2w);
    k_nodeab<<<282, 256, 0, stream>>>(2, 0, 0, Wn1, bn1, Wn2, bn2, We1, be1,
                                      hc, mi, c0, c1, Ap, BF);
    k_final<<<128, 256, 0, stream>>>(hc, rev, out);
}

// Round 13
// 381.560 us; speedup vs baseline: 1.0867x; 1.0747x over previous
//
#include <hip/hip_runtime.h>
#include <hip/hip_bf16.h>

typedef unsigned long long u64;
typedef unsigned int u32;
typedef unsigned short u16;

#define NN   512
#define DIMF 64
#define E2   260
#define KPAD 272
#define MD   17
#define MH   68
#define NH1  128
#define K0   460
#define K1   358
#define K2   307
#define KT   1125
#define O1   460
#define O2   818
#define PADU 1152
#define AS   272
// 64-sender tiles per receiver, one wave each (2 MFMA acc sets of 32)
#define NT0  8
#define NT1  6
#define NT2  5
#define T0T   (K0*NT0)          // 3680
#define T01T  (T0T + K1*NT1)    // 5828
#define TTOT  (T01T + K2*NT2)   // 7363
#define PBLK  ((TTOT+3)/4)      // 1841
#define MSTR  40                // u16 stride of m-repack rows (80 B: conflict-free, R6-proven)
#define WVLDS 5120              // per-wave LDS scratch bytes

typedef __attribute__((ext_vector_type(8)))  short short8;
typedef __attribute__((ext_vector_type(16))) float f32x16;

union SF  { int4 i4; u16 us[8]; u32 w[4]; short8 v; };
union F4U { float4 v; float2 h[2]; float f[4]; u32 w[4]; };

__device__ __forceinline__ float fast_exp2(float x){
#if __has_builtin(__builtin_amdgcn_exp2f)
    return __builtin_amdgcn_exp2f(x);
#else
    return __expf(x * 0.6931471805599453f);
#endif
}
__device__ __forceinline__ float fast_rcp(float x){
#if __has_builtin(__builtin_amdgcn_rcpf)
    return __builtin_amdgcn_rcpf(x);
#else
    return __fdividef(1.0f, x);
#endif
}
__device__ __forceinline__ float siluf(float x){
    return x * fast_rcp(1.0f + fast_exp2(x * -1.4426950408889634f));
}
__device__ __forceinline__ float sigf(float x){
    return fast_rcp(1.0f + fast_exp2(x * -1.4426950408889634f));
}
__device__ __forceinline__ u16 bf16_rne(float f){
    u32 u = __float_as_uint(f);
    u += 0x7FFFu + ((u >> 16) & 1u);
    return (u16)(u >> 16);
}
__device__ __forceinline__ float bf16f(u16 h){
    return __uint_as_float(((u32)h) << 16);
}
__device__ __forceinline__ void lgkm_wait(){
#if __has_builtin(__builtin_amdgcn_s_waitcnt)
    __builtin_amdgcn_s_waitcnt(0xC07F);   // lgkmcnt(0)
#endif
}
// packed float2 helpers (SLP-friendly -> v_pk_fma_f32 / v_pk_add_f32 / v_pk_mul_f32)
__device__ __forceinline__ float2 f2add(float2 a, float2 b){ return float2{a.x+b.x, a.y+b.y}; }
__device__ __forceinline__ float2 f2mul(float2 a, float2 b){ return float2{a.x*b.x, a.y*b.y}; }
__device__ __forceinline__ float2 f2fma(float2 a, float2 b, float2 c){
    return float2{fmaf(a.x,b.x,c.x), fmaf(a.y,b.y,c.y)};
}
__device__ __forceinline__ float2 silu2(float2 p){
    float2 t = f2mul(p, float2{-1.4426950408889634f, -1.4426950408889634f});
    float ex = fast_exp2(t.x), ey = fast_exp2(t.y);
    float rx = fast_rcp(1.0f + ex), ry = fast_rcp(1.0f + ey);
    return float2{p.x*rx, p.y*ry};
}
// truncation-split bf16 pack: hi = upper16(s) via v_perm, lo = s - trunc(s) (then trunc)
__device__ __forceinline__ void pack2(float2 s, u32& hpk, u32& lpk){
    u32 bx = __float_as_uint(s.x), by = __float_as_uint(s.y);
    hpk = __builtin_amdgcn_perm(by, bx, 0x07060302u);
    float lx = s.x - __uint_as_float(bx & 0xFFFF0000u);
    float ly = s.y - __uint_as_float(by & 0xFFFF0000u);
    lpk = __builtin_amdgcn_perm(__float_as_uint(ly), __float_as_uint(lx), 0x07060302u);
}

// ============ fused prep: ug bitmasks + pooling scores + weight fragments ===
__global__ __launch_bounds__(256) void k_pre(
    const float* __restrict__ edge, const float* __restrict__ feat,
    const float* __restrict__ wp, const float* __restrict__ bp,
    const float* __restrict__ We2, const float* __restrict__ Wc1,
    const float* __restrict__ We1, const float* __restrict__ be2,
    const float* __restrict__ bc1, const float* __restrict__ Wc2,
    u64* __restrict__ ugw, float* __restrict__ scores,
    u16* __restrict__ W2f, u16* __restrict__ Wc1f,
    float* __restrict__ wdP, float* __restrict__ weP, float* __restrict__ be2P,
    float* __restrict__ bc1P, float* __restrict__ Wc2P, u64* __restrict__ ug2w){
    int blk = blockIdx.x, t = threadIdx.x;
    if (blk < 128){                      // ug row bitmasks, 4 rows/block
        int i = blk*4 + (t>>6); int lane = t&63;
        const float* row = edge + (size_t)i*NN;
        for (int w = 0; w < 8; w++){
            u64 m = __ballot(row[w*64+lane] != 0.0f);
            if (lane == 0) ugw[i*8+w] = m;
        }
        return;
    }
    if (blk < 134){                      // pooling scores
        int gid = (blk-128)*256 + t; if (gid >= 3*NN) return;
        int l = gid>>9, n = gid&511;
        float s = bp[l];
        for (int d = 0; d < DIMF; d++) s = fmaf(feat[n*DIMF+d], wp[l*DIMF+d], s);
        scores[gid] = sigf(s);
        return;
    }
    int idx = (blk-134)*256 + t;
    if (idx < 52224){                    // We2 frags interleaved hi/lo: [jl][c17][hl2][lane][8]
        int e = idx&7, lane = (idx>>3)&63, hl = (idx>>9)&1, c = (idx>>10)%17, jl = idx/17408;
        int q = lane>>5, nn = lane&31;
        int k = c*16 + q*8 + e;
        float v = (k < E2 && nn < MD) ? We2[jl*E2*MD + k*MD + nn] : 0.0f;
        u16 hi = bf16_rne(v);
        W2f[idx] = hl ? bf16_rne(v - bf16f(hi)) : hi;
        return;
    }
    idx -= 52224;
    if (idx < 9216){                     // Wc1 frags: [jl][T3][c2][lane][8]
        int e = idx & 7, lane = (idx>>3)&63, c2 = (idx>>9)&1, T = (idx>>10)%3, jl = idx/3072;
        int q = lane>>5, nn = lane&31;
        int o = c2*16 + q*8 + e, h = T*32 + nn;
        float v = (o < MD && h < MH) ? Wc1[jl*MD*MH + o*MH + h] : 0.0f;
        Wc1f[idx] = bf16_rne(v);
        return;
    }
    idx -= 9216;
    if (idx < 816){ int jl = idx/KPAD, k = idx%KPAD;
        wdP[idx] = (k < E2) ? We1[jl*130*E2 + 128*E2 + k] : 0.0f; return; }
    idx -= 816;
    if (idx < 816){ int jl = idx/KPAD, k = idx%KPAD;
        weP[idx] = (k < E2) ? We1[jl*130*E2 + 129*E2 + k] : 0.0f; return; }
    idx -= 816;
    if (idx < 96){ int jl = idx/32, o = idx%32;
        be2P[idx] = (o < MD) ? be2[jl*MD+o] : 0.0f; return; }
    idx -= 96;
    if (idx < 288){ int jl = idx/96, h = idx%96;
        bc1P[idx] = (h < MH) ? bc1[jl*MH+h] : 0.0f; return; }
    idx -= 288;
    if (idx < 288){ int jl = idx/96, h = idx%96;
        Wc2P[idx] = (h < MH) ? Wc2[jl*MH+h] : 0.0f; return; }
    idx -= 288;
    if (idx < 4096){ ug2w[idx] = 0ULL; return; }   // zero for k_sortug2's atomicOr
}

// ============ fused: bitonic sort (3 blocks) + ug2 bitset matmul (64 blocks) =
__global__ __launch_bounds__(512) void k_sortug2(
    const float* __restrict__ scores, const u64* __restrict__ ugw,
    float* __restrict__ svals, int* __restrict__ sidx, int* __restrict__ rev,
    u64* __restrict__ ug2w){
    int blk = blockIdx.x, t = threadIdx.x;
    if (blk < 3){
        int l = blk;
        __shared__ float sk[NN];
        __shared__ int   si[NN];
        sk[t] = scores[l*NN+t]; si[t] = t; rev[l*NN+t] = -1;
        __syncthreads();
        for (int k = 2; k <= NN; k <<= 1){
            for (int jj = k>>1; jj > 0; jj >>= 1){
                int p = t ^ jj;
                if (p > t){
                    float ka = sk[t], kb = sk[p];
                    int ia = si[t], ib = si[p];
                    bool before = (ka > kb) || (ka == kb && ia < ib);
                    bool sw = ((t & k) == 0) ? (!before) : before;
                    if (sw){ sk[t]=kb; sk[p]=ka; si[t]=ib; si[p]=ia; }
                }
                __syncthreads();
            }
        }
        svals[l*NN+t] = sk[t]; sidx[l*NN+t] = si[t];
        int kcnt = (l==0)?K0:(l==1)?K1:K2;
        if (t < kcnt) rev[l*NN + si[t]] = t;
    } else {
        // (i, w, kc): row i, out-word w, row-mask word kc. Iterate SET BITS only.
        int gid = (blk-3)*512 + t;       // 32768 total
        int i  = gid >> 6;
        int w  = (gid >> 3) & 7;
        int kc = gid & 7;
        u64 rm = ugw[i*8 + kc];
        u64 acc = 0;
        int base = kc*64;
        while (rm){
            int k2 = __builtin_ctzll(rm);
            rm &= rm - 1;
            acc |= ugw[(base + k2)*8 + w];
        }
        if (acc) atomicOr(&ug2w[i*8 + w], acc);
    }
}

// ============ A/B precompute ================================================
// A row-major per node (zero-padded k 260..271); B in BF[k>>3][u][k&7] groups.
__device__ __forceinline__ void ab_comp(int jl, const float* __restrict__ We1,
                                        const float* __restrict__ be1, float hval,
                                        int u, int lane,
                                        float* __restrict__ Ap, float* __restrict__ BF){
    const float* W = We1 + jl*130*E2;
    int r  = 4*lane;
    int rt = 256 + lane;
    int rtc = (lane < 4) ? rt : 256;
    F4U av; av.v = *(const float4*)(be1 + jl*E2 + r);
    F4U bv; bv.f[0]=bv.f[1]=bv.f[2]=bv.f[3]=0.0f;
    float avx = be1[jl*E2 + rtc];
    float bvx = 0.0f;
    for (int d = 0; d < DIMF; d++){
        float hv = __shfl(hval, d);
        F4U w1; w1.v = *(const float4*)(W + d*E2 + r);
        F4U w2; w2.v = *(const float4*)(W + (DIMF+d)*E2 + r);
#pragma unroll
        for (int i = 0; i < 4; i++){
            av.f[i] = fmaf(hv, w1.f[i], av.f[i]);
            bv.f[i] = fmaf(hv, w2.f[i], bv.f[i]);
        }
        avx = fmaf(hv, W[d*E2 + rtc], avx);
        bvx = fmaf(hv, W[(DIMF+d)*E2 + rtc], bvx);
    }
    *(float4*)(Ap + u*AS + r) = av.v;
    *(float4*)(BF + ((size_t)(lane>>1)*PADU + u)*8 + (lane&1)*4) = bv.v;
    if (lane < 16){                     // k = 256..271; zero-pad beyond 259
        int k = 256 + lane;
        float aval = (lane < 4) ? avx : 0.0f;
        float bval = (lane < 4) ? bvx : 0.0f;
        Ap[u*AS + k] = aval;
        BF[((size_t)(k>>3)*PADU + u)*8 + (k&7)] = bval;
    }
}

// ============ gather + AB(layer0) + init mi/c0/c1 ===========================
__global__ __launch_bounds__(256) void k_gab(
    const float* __restrict__ feat, const float* __restrict__ coor,
    const float* __restrict__ svals, const int* __restrict__ sidx,
    const float* __restrict__ We1, const float* __restrict__ be1,
    float* __restrict__ hc, float* __restrict__ c0, float* __restrict__ c1,
    float* __restrict__ mi, float* __restrict__ Ap, float* __restrict__ BF){
    int t = threadIdx.x; int u = blockIdx.x*4 + (t>>6); if (u >= KT) return;
    int lane = t&63;
    int l = (u<K0)?0:(u<O2)?1:2;
    int a = u - ((l==0)?0:(l==1)?O1:O2);
    int org = sidx[l*NN+a];
    float val = svals[l*NN+a];
    float hval = feat[org*DIMF+lane]*val;
    hc[u*DIMF+lane] = hval;
    if (lane < 3){ float c = coor[org*3+lane]; c0[u*4+lane]=c; c1[u*4+lane]=c; }
    if (lane == 3){ c0[u*4+3]=0.0f; c1[u*4+3]=0.0f; }
    if (lane < 20) mi[u*20+lane] = 0.0f;
    ab_comp(0, We1, be1, hval, u, lane, Ap, BF);
}

// ============ per-pair edge MLP via MFMA =====================================
// wave = (receiver u, 64-sender tile): two 32-pair MFMA acc sets.
// 2-term bf16 split (R12-verified accurate: absmax 2.1e6 < 3.6e6 threshold):
// acc = shi@Whi + slo@Whi == s @ bf16RNE(We2). Rotating-register software
// pipeline (R9-proven no-spill at VGPR 64); ping-pong unroll-2 spilled (R12).
// launch_bounds(256,4): PROVEN optimum (R8/R10: any lower budget spills).
template<int DOCW>
__global__ __launch_bounds__(256, 4) void k_pair(
    int jl,
    const float* __restrict__ Ap, const float* __restrict__ BF,
    const u16* __restrict__ W2f, const u16* __restrict__ Wc1f,
    const float* __restrict__ wdP, const float* __restrict__ weP,
    const float* __restrict__ be2P, const float* __restrict__ bc1P,
    const float* __restrict__ Wc2P, const float* __restrict__ bc2,
    const float* __restrict__ cin, float* __restrict__ cout,
    float* __restrict__ mi, const int* __restrict__ sidx,
    const u64* __restrict__ ug2w){
    __shared__ __align__(16) char sWK[4*WVLDS];
    __shared__ __align__(16) char sWD[1088];
    __shared__ __align__(16) char sWE[1088];
    int t = threadIdx.x;
    if (t < 68)       ((float4*)sWD)[t]    = *(const float4*)(wdP + jl*KPAD + 4*t);
    else if (t < 136) ((float4*)sWE)[t-68] = *(const float4*)(weP + jl*KPAD + 4*(t-68));
    int wid0 = blockIdx.x*4 + (t>>6);
    int lane = t&63, n = lane&31, q = lane>>5;
    bool dead = (wid0 >= TTOT);
    int wid = dead ? (TTOT-1) : wid0;
    int l, kl, off, a, tile;
    if (wid < T0T)       { l=0; kl=K0; off=0;  a = wid>>3; tile = wid&7; }
    else if (wid < T01T) { int w = wid-T0T;  l=1; kl=K1; off=O1; a = w/NT1; tile = w - a*NT1; }
    else                 { int w = wid-T01T; l=2; kl=K2; off=O2; a = w/NT2; tile = w - a*NT2; }
    int u = off + a;
    int b0 = tile*64 + n, b1 = b0 + 32;
    float act0 = (b0 < kl) ? 1.0f : 0.0f;
    float act1 = (b1 < kl) ? 1.0f : 0.0f;
    int b0c = min(b0, kl-1), b1c = min(b1, kl-1);
    int ub0 = off + b0c, ub1 = off + b1c;
    int ia  = sidx[l*NN+a];
    int ib0 = sidx[l*NN+b0c], ib1 = sidx[l*NN+b1c];
    float ef0 = act0 * (float)((ug2w[ia*8 + (ib0>>6)] >> (ib0&63)) & 1ULL);
    float ef1 = act1 * (float)((ug2w[ia*8 + (ib1>>6)] >> (ib1&63)) & 1ULL);
    F4U ca;  ca.v  = ((const float4*)cin)[u];
    F4U cb0; cb0.v = ((const float4*)cin)[ub0];
    F4U cb1; cb1.v = ((const float4*)cin)[ub1];
    float tx0 = ca.f[0]-cb0.f[0], ty0 = ca.f[1]-cb0.f[1], tz0 = ca.f[2]-cb0.f[2];
    float tx1 = ca.f[0]-cb1.f[0], ty1 = ca.f[1]-cb1.f[1], tz1 = ca.f[2]-cb1.f[2];
    float dd0 = tx0*tx0 + ty0*ty0 + tz0*tz0;
    float dd1 = tx1*tx1 + ty1*ty1 + tz1*tz1;

    char* myk = sWK + (t>>6)*WVLDS;
    {   // stage A for this wave's receiver
        const float* Au = Ap + u*AS;
        ((float4*)myk)[lane] = *(const float4*)(Au + 4*lane);
        if (lane < 4) ((float4*)myk)[64+lane] = *(const float4*)(Au + 256 + 4*lane);
    }
    __syncthreads();

    const float* pB0 = BF + ((size_t)q*PADU + ub0)*8;
    const float* pB1 = BF + ((size_t)q*PADU + ub1)*8;
    const u16*   pW  = W2f + jl*17408 + lane*8;
    const char*  pA  = myk + q*32;
    const char*  pWD = sWD + q*32;
    const char*  pWE = sWE + q*32;

    f32x16 acc0, acc1;
#pragma unroll
    for (int r = 0; r < 16; r++){ acc0[r] = 0.0f; acc1[r] = 0.0f; }

    // prologue loads for c=0 (rotating pipeline, R9 structure; no Wlo term)
    F4U nb0a, nb0b, nb1a, nb1b; SF nwh;
    nb0a.v = *(const float4*)(pB0);     nb0b.v = *(const float4*)(pB0 + 4);
    nb1a.v = *(const float4*)(pB1);     nb1b.v = *(const float4*)(pB1 + 4);
    nwh.i4 = *(const int4*)(pW);

    float2 DD0{dd0,dd0}, EF0{ef0,ef0}, DD1{dd1,dd1}, EF1{ef1,ef1};

    for (int c = 0; c < 17; c++){
        F4U b0a = nb0a, b0b = nb0b, b1a = nb1a, b1b = nb1b;
        SF  wh  = nwh;
        pB0 += 2*PADU*8; pB1 += 2*PADU*8; pW += 1024;
        if (c < 16){   // issue c+1's global loads before computing c
            nb0a.v = *(const float4*)(pB0);     nb0b.v = *(const float4*)(pB0 + 4);
            nb1a.v = *(const float4*)(pB1);     nb1b.v = *(const float4*)(pB1 + 4);
            nwh.i4 = *(const int4*)(pW);
        }
        F4U a0, a1, w0, w1, e0, e1;
        a0.v = *(const float4*)(pA);       a1.v = *(const float4*)(pA + 16);
        w0.v = *(const float4*)(pWD);      w1.v = *(const float4*)(pWD + 16);
        e0.v = *(const float4*)(pWE);      e1.v = *(const float4*)(pWE + 16);
        pA += 64; pWD += 64; pWE += 64;

        SF shi0, slo0, shi1, slo1;
#pragma unroll
        for (int h = 0; h < 2; h++){
            float2 p00 = f2fma(EF0, e0.h[h], f2fma(DD0, w0.h[h], f2add(a0.h[h], b0a.h[h])));
            float2 p01 = f2fma(EF0, e1.h[h], f2fma(DD0, w1.h[h], f2add(a1.h[h], b0b.h[h])));
            float2 p10 = f2fma(EF1, e0.h[h], f2fma(DD1, w0.h[h], f2add(a0.h[h], b1a.h[h])));
            float2 p11 = f2fma(EF1, e1.h[h], f2fma(DD1, w1.h[h], f2add(a1.h[h], b1b.h[h])));
            pack2(silu2(p00), shi0.w[h],   slo0.w[h]);
            pack2(silu2(p01), shi0.w[2+h], slo0.w[2+h]);
            pack2(silu2(p10), shi1.w[h],   slo1.w[h]);
            pack2(silu2(p11), shi1.w[2+h], slo1.w[2+h]);
        }
        acc0 = __builtin_amdgcn_mfma_f32_32x32x16_bf16(shi0.v, wh.v, acc0, 0, 0, 0);
        acc0 = __builtin_amdgcn_mfma_f32_32x32x16_bf16(slo0.v, wh.v, acc0, 0, 0, 0);
        acc1 = __builtin_amdgcn_mfma_f32_32x32x16_bf16(shi1.v, wh.v, acc1, 0, 0, 0);
        acc1 = __builtin_amdgcn_mfma_f32_32x32x16_bf16(slo1.v, wh.v, acc1, 0, 0, 0);
    }

    // ---- m = silu(acc + be2); masked m_i sum; (DOCW) repack to LDS bf16
    float be2v = be2P[jl*32 + n];
    u16* mlds = (u16*)myk;               // overwrites A stage (done with it)
    float msum = 0.0f;
#pragma unroll
    for (int r = 0; r < 16; r++){
        int row = (r&3) + 8*(r>>2) + 4*q;
        float m0 = siluf(acc0[r] + be2v);
        float m1 = siluf(acc1[r] + be2v);
        m0 = (tile*64 + row      < kl) ? m0 : 0.0f;
        m1 = (tile*64 + 32 + row < kl) ? m1 : 0.0f;
        msum += m0 + m1;
        if (DOCW){
            mlds[row*MSTR + n]        = bf16_rne(m0);
            mlds[(row+32)*MSTR + n]   = bf16_rne(m1);
        }
    }
    msum += __shfl_xor(msum, 32);
    if (!dead && lane < MD) atomicAdd(&mi[u*20 + lane], msum);

    if (DOCW){
        lgkm_wait();
        const char* mb = (const char*)mlds;
        float gx = 0.0f, gy = 0.0f, gz = 0.0f;
        float bc2v = bc2[jl];
#pragma unroll
        for (int S = 0; S < 2; S++){
            SF af0, af1;
            af0.i4 = *(const int4*)(mb + (S*32+n)*(MSTR*2) + q*16);
            af1.i4 = *(const int4*)(mb + (S*32+n)*(MSTR*2) + 32 + q*16);
            float cwp[16];
#pragma unroll
            for (int r = 0; r < 16; r++) cwp[r] = 0.0f;
            for (int T = 0; T < 3; T++){
                SF bb0, bb1;
                bb0.i4 = *(const int4*)(Wc1f + jl*3072 + T*1024 +       lane*8);
                bb1.i4 = *(const int4*)(Wc1f + jl*3072 + T*1024 + 512 + lane*8);
                f32x16 p2;
#pragma unroll
                for (int r = 0; r < 16; r++) p2[r] = 0.0f;
                p2 = __builtin_amdgcn_mfma_f32_32x32x16_bf16(af0.v, bb0.v, p2, 0, 0, 0);
                p2 = __builtin_amdgcn_mfma_f32_32x32x16_bf16(af1.v, bb1.v, p2, 0, 0, 0);
                float bc1v = bc1P[jl*96 + T*32 + n];
                float wc2v = Wc2P[jl*96 + T*32 + n];
#pragma unroll
                for (int r = 0; r < 16; r++)
                    cwp[r] = fmaf(siluf(p2[r] + bc1v), wc2v, cwp[r]);
            }
#pragma unroll
            for (int r = 0; r < 16; r++){
                int row  = (r&3) + 8*(r>>2) + 4*q + S*32;
                int brow = tile*64 + row;
                F4U cbr; cbr.v = ((const float4*)cin)[off + min(brow, kl-1)];
                float cw = cwp[r] + ((n == 0) ? bc2v : 0.0f);
                cw = (brow < kl) ? cw : 0.0f;
                gx = fmaf(cw, ca.f[0]-cbr.f[0], gx);
                gy = fmaf(cw, ca.f[1]-cbr.f[1], gy);
                gz = fmaf(cw, ca.f[2]-cbr.f[2], gz);
            }
        }
#pragma unroll
        for (int s = 1; s < 64; s <<= 1){
            gx += __shfl_xor(gx, s); gy += __shfl_xor(gy, s); gz += __shfl_xor(gz, s);
        }
        if (!dead && lane == 0){
            atomicAdd(&cout[u*4+0], gx);
            atomicAdd(&cout[u*4+1], gy);
            atomicAdd(&cout[u*4+2], gz);
        }
    }
}

// ============ node MLP + (optionally) AB for next layer + inits ==============
__global__ __launch_bounds__(256) void k_nodeab(
    int jl, int donext, int docopy,
    const float* __restrict__ Wn1, const float* __restrict__ bn1,
    const float* __restrict__ Wn2, const float* __restrict__ bn2,
    const float* __restrict__ We1, const float* __restrict__ be1,
    float* __restrict__ hc, float* __restrict__ mi,
    const float* __restrict__ ccur, float* __restrict__ cnext,
    float* __restrict__ Ap, float* __restrict__ BF){
    int t = threadIdx.x; int u = blockIdx.x*4 + (t>>6); if (u >= KT) return;
    int lane = t&63;
    float hval = hc[u*DIMF+lane];
    float mval = (lane < MD) ? mi[u*20+lane] : 0.0f;
    const float* W1 = Wn1 + jl*(DIMF+MD)*NH1;
    float v0 = bn1[jl*NH1+lane], v1 = bn1[jl*NH1+lane+64];
    for (int d = 0; d < DIMF; d++){
        float x = __shfl(hval, d);
        v0 = fmaf(x, W1[d*NH1+lane],    v0);
        v1 = fmaf(x, W1[d*NH1+lane+64], v1);
    }
    for (int d = 0; d < MD; d++){
        float x = __shfl(mval, d);
        v0 = fmaf(x, W1[(DIMF+d)*NH1+lane],    v0);
        v1 = fmaf(x, W1[(DIMF+d)*NH1+lane+64], v1);
    }
    float s0 = siluf(v0), s1 = siluf(v1);
    const float* W2 = Wn2 + jl*NH1*DIMF;
    float h = bn2[jl*DIMF+lane];
    for (int i = 0; i < 64; i++) h = fmaf(__shfl(s0, i), W2[i*DIMF+lane], h);
    for (int i = 0; i < 64; i++) h = fmaf(__shfl(s1, i), W2[(64+i)*DIMF+lane], h);
    float hn = fmaxf(0.0f, fmaf(2.0f, hval, h));
    hc[u*DIMF+lane] = hn;
    if (donext){
        if (lane < 20) mi[u*20+lane] = 0.0f;
        if (docopy && lane < 4) cnext[u*4+lane] = ccur[u*4+lane];
        ab_comp(jl+1, We1, be1, hn, u, lane, Ap, BF);
    }
}

// ============ scatter + 3-level max =========================================
__global__ void k_final(const float* __restrict__ hc, const int* __restrict__ rev,
                        float* __restrict__ out){
    int gid = blockIdx.x*blockDim.x + threadIdx.x;
    if (gid >= NN*DIMF) return;
    int nn = gid>>6, d = gid&63;
    float v = 0.0f;
    int a0 = rev[0*NN+nn]; if (a0 >= 0) v = fmaxf(v, hc[(0  + a0)*DIMF + d]);
    int a1 = rev[1*NN+nn]; if (a1 >= 0) v = fmaxf(v, hc[(O1 + a1)*DIMF + d]);
    int a2 = rev[2*NN+nn]; if (a2 >= 0) v = fmaxf(v, hc[(O2 + a2)*DIMF + d]);
    out[gid] = v;
}

extern "C" void kernel_launch(void* const* d_in, const int* in_sizes, int n_in,
                              void* d_out, int out_size, void* d_ws, size_t ws_size,
                              hipStream_t stream) {
    (void)in_sizes; (void)n_in; (void)out_size; (void)ws_size;
    const float* feat = (const float*)d_in[0];
    const float* coor = (const float*)d_in[1];
    const float* edge = (const float*)d_in[2];
    const float* We1  = (const float*)d_in[3];
    const float* be1  = (const float*)d_in[4];
    const float* We2  = (const float*)d_in[5];
    const float* be2  = (const float*)d_in[6];
    const float* Wc1  = (const float*)d_in[7];
    const float* bc1  = (const float*)d_in[8];
    const float* Wc2  = (const float*)d_in[9];
    const float* bc2  = (const float*)d_in[10];
    const float* Wn1  = (const float*)d_in[11];
    const float* bn1  = (const float*)d_in[12];
    const float* Wn2  = (const float*)d_in[13];
    const float* bn2  = (const float*)d_in[14];
    const float* wp   = (const float*)d_in[15];
    const float* bp   = (const float*)d_in[16];
    float* out = (float*)d_out;

    char* wsb = (char*)d_ws;
    u64*   ugw    = (u64*)  (wsb + 0);         // 32768
    u64*   ug2w   = (u64*)  (wsb + 32768);     // 32768
    float* scores = (float*)(wsb + 65536);     // 6144
    float* svals  = (float*)(wsb + 71680);     // 6144
    int*   sidx   = (int*)  (wsb + 77824);     // 6144
    int*   rev    = (int*)  (wsb + 83968);     // 6144
    float* c0     = (float*)(wsb + 90112);     // 18432
    float* c1     = (float*)(wsb + 108544);    // 18432
    float* mi     = (float*)(wsb + 126976);    // 90112
    float* hc     = (float*)(wsb + 217088);    // 288256
    float* Ap     = (float*)(wsb + 505344);    // 1224192
    float* BF     = (float*)(wsb + 1729536);   // 1253376 (34*1152*8*4)
    u16*   W2f    = (u16*)  (wsb + 2982912);   // 104448  (3*17*2*512*2)
    u16*   Wc1f   = (u16*)  (wsb + 3087360);   // 18432
    float* wdP    = (float*)(wsb + 3105792);   // 3328
    float* weP    = (float*)(wsb + 3109120);   // 3328
    float* be2P   = (float*)(wsb + 3112448);   // 384
    float* bc1P   = (float*)(wsb + 3112832);   // 1152
    float* Wc2P   = (float*)(wsb + 3113984);   // 1152  (end ~3.12 MB)

    k_pre<<<399, 256, 0, stream>>>(edge, feat, wp, bp, We2, Wc1, We1, be2, bc1, Wc2,
                                   ugw, scores, W2f, Wc1f,
                                   wdP, weP, be2P, bc1P, Wc2P, ug2w);
    k_sortug2<<<67, 512, 0, stream>>>(scores, ugw, svals, sidx, rev, ug2w);
    k_gab<<<282, 256, 0, stream>>>(feat, coor, svals, sidx, We1, be1,
                                   hc, c0, c1, mi, Ap, BF);
    // layer 0: cin=c0, cout=c1
    k_pair<1><<<PBLK, 256, 0, stream>>>(0, Ap, BF, W2f, Wc1f,
                                        wdP, weP, be2P, bc1P, Wc2P, bc2,
                                        c0, c1, mi, sidx, ug2w);
    k_nodeab<<<282, 256, 0, stream>>>(0, 1, 1, Wn1, bn1, Wn2, bn2, We1, be1,
                                      hc, mi, c1, c0, Ap, BF);
    // layer 1: cin=c1, cout=c0 (pre-initialized to c1 by k_nodeab)
    k_pair<1><<<PBLK, 256, 0, stream>>>(1, Ap, BF, W2f, Wc1f,
                                        wdP, weP, be2P, bc1P, Wc2P, bc2,
                                        c1, c0, mi, sidx, ug2w);
    k_nodeab<<<282, 256, 0, stream>>>(1, 1, 0, Wn1, bn1, Wn2, bn2, We1, be1,
                                      hc, mi, c0, c1, Ap, BF);
    // layer 2: coords output unused -> no coord MLP instantiation
    k_pair<0><<<PBLK, 256, 0, stream>>>(2, Ap, BF, W2f, Wc1f,
                                        wdP, weP, be2P, bc1P, Wc2P, bc2,
                                        c0, c1, mi, sidx, ug2w);
    k_nodeab<<<282, 256, 0, stream>>>(2, 0, 0, Wn1, bn1, Wn2, bn2, We1, be1,
                                      hc, mi, c0, c1, Ap, BF);
    k_final<<<128, 256, 0, stream>>>(hc, rev, out);
}

// Round 14
// 372.516 us; speedup vs baseline: 1.1131x; 1.0243x over previous
//
#include <hip/hip_runtime.h>
#include <hip/hip_bf16.h>

typedef unsigned long long u64;
typedef unsigned int u32;
typedef unsigned short u16;

#define NN   512
#define DIMF 64
#define E2   260
#define KPAD 272
#define MD   17
#define MH   68
#define NH1  128
#define K0   460
#define K1   358
#define K2   307
#define KT   1125
#define O1   460
#define O2   818
#define PADU 1152
#define AS   272
// 64-sender tiles per receiver, one wave each (2 MFMA acc sets of 32)
#define NT0  8
#define NT1  6
#define NT2  5
#define T0T   (K0*NT0)          // 3680
#define T01T  (T0T + K1*NT1)    // 5828
#define TTOT  (T01T + K2*NT2)   // 7363
#define PBLK  ((TTOT+3)/4)      // 1841
#define MSTR  40                // u16 stride of m-repack rows (80 B: conflict-free, R6-proven)
#define WVLDS 5120              // per-wave LDS scratch bytes

typedef __attribute__((ext_vector_type(8)))  short short8;
typedef __attribute__((ext_vector_type(16))) float f32x16;

union SF  { int4 i4; u16 us[8]; u32 w[4]; short8 v; };
union F4U { float4 v; float2 h[2]; float f[4]; u32 w[4]; };

__device__ __forceinline__ float fast_exp2(float x){
#if __has_builtin(__builtin_amdgcn_exp2f)
    return __builtin_amdgcn_exp2f(x);
#else
    return __expf(x * 0.6931471805599453f);
#endif
}
__device__ __forceinline__ float fast_rcp(float x){
#if __has_builtin(__builtin_amdgcn_rcpf)
    return __builtin_amdgcn_rcpf(x);
#else
    return __fdividef(1.0f, x);
#endif
}
__device__ __forceinline__ float siluf(float x){
    return x * fast_rcp(1.0f + fast_exp2(x * -1.4426950408889634f));
}
__device__ __forceinline__ float sigf(float x){
    return fast_rcp(1.0f + fast_exp2(x * -1.4426950408889634f));
}
__device__ __forceinline__ u16 bf16_rne(float f){
    u32 u = __float_as_uint(f);
    u += 0x7FFFu + ((u >> 16) & 1u);
    return (u16)(u >> 16);
}
__device__ __forceinline__ float bf16f(u16 h){
    return __uint_as_float(((u32)h) << 16);
}
// packed RNE bf16x2 (v_cvt_pk_bf16_f32 on gfx950)
__device__ __forceinline__ u32 pk_bf16(float x, float y){
    float2 f2; f2.x = x; f2.y = y;
    __hip_bfloat162 h = __float22bfloat162_rn(f2);
    union { __hip_bfloat162 b; u32 u; } cv; cv.b = h;
    return cv.u;
}
__device__ __forceinline__ void lgkm_wait(){
#if __has_builtin(__builtin_amdgcn_s_waitcnt)
    __builtin_amdgcn_s_waitcnt(0xC07F);   // lgkmcnt(0)
#endif
}
// packed float2 helpers (SLP-friendly -> v_pk_fma_f32 / v_pk_add_f32 / v_pk_mul_f32)
__device__ __forceinline__ float2 f2add(float2 a, float2 b){ return float2{a.x+b.x, a.y+b.y}; }
__device__ __forceinline__ float2 f2mul(float2 a, float2 b){ return float2{a.x*b.x, a.y*b.y}; }
__device__ __forceinline__ float2 f2fma(float2 a, float2 b, float2 c){
    return float2{fmaf(a.x,b.x,c.x), fmaf(a.y,b.y,c.y)};
}
__device__ __forceinline__ float2 silu2(float2 p){
    float2 t = f2mul(p, float2{-1.4426950408889634f, -1.4426950408889634f});
    float ex = fast_exp2(t.x), ey = fast_exp2(t.y);
    float rx = fast_rcp(1.0f + ex), ry = fast_rcp(1.0f + ey);
    return float2{p.x*rx, p.y*ry};
}

// ============ fused prep: ug bitmasks + pooling scores + weight fragments ===
__global__ __launch_bounds__(256) void k_pre(
    const float* __restrict__ edge, const float* __restrict__ feat,
    const float* __restrict__ wp, const float* __restrict__ bp,
    const float* __restrict__ We2, const float* __restrict__ Wc1,
    const float* __restrict__ We1, const float* __restrict__ be2,
    const float* __restrict__ bc1, const float* __restrict__ Wc2,
    u64* __restrict__ ugw, float* __restrict__ scores,
    u16* __restrict__ W2f, u16* __restrict__ Wc1f,
    float* __restrict__ wdP, float* __restrict__ weP, float* __restrict__ be2P,
    float* __restrict__ bc1P, float* __restrict__ Wc2P, u64* __restrict__ ug2w){
    int blk = blockIdx.x, t = threadIdx.x;
    if (blk < 128){                      // ug row bitmasks, 4 rows/block
        int i = blk*4 + (t>>6); int lane = t&63;
        const float* row = edge + (size_t)i*NN;
        for (int w = 0; w < 8; w++){
            u64 m = __ballot(row[w*64+lane] != 0.0f);
            if (lane == 0) ugw[i*8+w] = m;
        }
        return;
    }
    if (blk < 134){                      // pooling scores
        int gid = (blk-128)*256 + t; if (gid >= 3*NN) return;
        int l = gid>>9, n = gid&511;
        float s = bp[l];
        for (int d = 0; d < DIMF; d++) s = fmaf(feat[n*DIMF+d], wp[l*DIMF+d], s);
        scores[gid] = sigf(s);
        return;
    }
    int idx = (blk-134)*256 + t;
    if (idx < 52224){                    // We2 frags interleaved hi/lo: [jl][c17][hl2][lane][8]
        int e = idx&7, lane = (idx>>3)&63, hl = (idx>>9)&1, c = (idx>>10)%17, jl = idx/17408;
        int q = lane>>5, nn = lane&31;
        int k = c*16 + q*8 + e;
        float v = (k < E2 && nn < MD) ? We2[jl*E2*MD + k*MD + nn] : 0.0f;
        u16 hi = bf16_rne(v);
        W2f[idx] = hl ? bf16_rne(v - bf16f(hi)) : hi;
        return;
    }
    idx -= 52224;
    if (idx < 9216){                     // Wc1 frags: [jl][T3][c2][lane][8]
        int e = idx & 7, lane = (idx>>3)&63, c2 = (idx>>9)&1, T = (idx>>10)%3, jl = idx/3072;
        int q = lane>>5, nn = lane&31;
        int o = c2*16 + q*8 + e, h = T*32 + nn;
        float v = (o < MD && h < MH) ? Wc1[jl*MD*MH + o*MH + h] : 0.0f;
        Wc1f[idx] = bf16_rne(v);
        return;
    }
    idx -= 9216;
    if (idx < 816){ int jl = idx/KPAD, k = idx%KPAD;
        wdP[idx] = (k < E2) ? We1[jl*130*E2 + 128*E2 + k] : 0.0f; return; }
    idx -= 816;
    if (idx < 816){ int jl = idx/KPAD, k = idx%KPAD;
        weP[idx] = (k < E2) ? We1[jl*130*E2 + 129*E2 + k] : 0.0f; return; }
    idx -= 816;
    if (idx < 96){ int jl = idx/32, o = idx%32;
        be2P[idx] = (o < MD) ? be2[jl*MD+o] : 0.0f; return; }
    idx -= 96;
    if (idx < 288){ int jl = idx/96, h = idx%96;
        bc1P[idx] = (h < MH) ? bc1[jl*MH+h] : 0.0f; return; }
    idx -= 288;
    if (idx < 288){ int jl = idx/96, h = idx%96;
        Wc2P[idx] = (h < MH) ? Wc2[jl*MH+h] : 0.0f; return; }
    idx -= 288;
    if (idx < 4096){ ug2w[idx] = 0ULL; return; }   // zero for k_sortug2's atomicOr
}

// ============ fused: bitonic sort (3 blocks) + ug2 bitset matmul (64 blocks) =
__global__ __launch_bounds__(512) void k_sortug2(
    const float* __restrict__ scores, const u64* __restrict__ ugw,
    float* __restrict__ svals, int* __restrict__ sidx, int* __restrict__ rev,
    u64* __restrict__ ug2w){
    int blk = blockIdx.x, t = threadIdx.x;
    if (blk < 3){
        int l = blk;
        __shared__ float sk[NN];
        __shared__ int   si[NN];
        sk[t] = scores[l*NN+t]; si[t] = t; rev[l*NN+t] = -1;
        __syncthreads();
        for (int k = 2; k <= NN; k <<= 1){
            for (int jj = k>>1; jj > 0; jj >>= 1){
                int p = t ^ jj;
                if (p > t){
                    float ka = sk[t], kb = sk[p];
                    int ia = si[t], ib = si[p];
                    bool before = (ka > kb) || (ka == kb && ia < ib);
                    bool sw = ((t & k) == 0) ? (!before) : before;
                    if (sw){ sk[t]=kb; sk[p]=ka; si[t]=ib; si[p]=ia; }
                }
                __syncthreads();
            }
        }
        svals[l*NN+t] = sk[t]; sidx[l*NN+t] = si[t];
        int kcnt = (l==0)?K0:(l==1)?K1:K2;
        if (t < kcnt) rev[l*NN + si[t]] = t;
    } else {
        // (i, w, kc): row i, out-word w, row-mask word kc. Iterate SET BITS only.
        int gid = (blk-3)*512 + t;       // 32768 total
        int i  = gid >> 6;
        int w  = (gid >> 3) & 7;
        int kc = gid & 7;
        u64 rm = ugw[i*8 + kc];
        u64 acc = 0;
        int base = kc*64;
        while (rm){
            int k2 = __builtin_ctzll(rm);
            rm &= rm - 1;
            acc |= ugw[(base + k2)*8 + w];
        }
        if (acc) atomicOr(&ug2w[i*8 + w], acc);
    }
}

// ============ A/B precompute ================================================
// A row-major per node (zero-padded k 260..271); B in BF[k>>3][u][k&7] groups.
__device__ __forceinline__ void ab_comp(int jl, const float* __restrict__ We1,
                                        const float* __restrict__ be1, float hval,
                                        int u, int lane,
                                        float* __restrict__ Ap, float* __restrict__ BF){
    const float* W = We1 + jl*130*E2;
    int r  = 4*lane;
    int rt = 256 + lane;
    int rtc = (lane < 4) ? rt : 256;
    F4U av; av.v = *(const float4*)(be1 + jl*E2 + r);
    F4U bv; bv.f[0]=bv.f[1]=bv.f[2]=bv.f[3]=0.0f;
    float avx = be1[jl*E2 + rtc];
    float bvx = 0.0f;
    for (int d = 0; d < DIMF; d++){
        float hv = __shfl(hval, d);
        F4U w1; w1.v = *(const float4*)(W + d*E2 + r);
        F4U w2; w2.v = *(const float4*)(W + (DIMF+d)*E2 + r);
#pragma unroll
        for (int i = 0; i < 4; i++){
            av.f[i] = fmaf(hv, w1.f[i], av.f[i]);
            bv.f[i] = fmaf(hv, w2.f[i], bv.f[i]);
        }
        avx = fmaf(hv, W[d*E2 + rtc], avx);
        bvx = fmaf(hv, W[(DIMF+d)*E2 + rtc], bvx);
    }
    *(float4*)(Ap + u*AS + r) = av.v;
    *(float4*)(BF + ((size_t)(lane>>1)*PADU + u)*8 + (lane&1)*4) = bv.v;
    if (lane < 16){                     // k = 256..271; zero-pad beyond 259
        int k = 256 + lane;
        float aval = (lane < 4) ? avx : 0.0f;
        float bval = (lane < 4) ? bvx : 0.0f;
        Ap[u*AS + k] = aval;
        BF[((size_t)(k>>3)*PADU + u)*8 + (k&7)] = bval;
    }
}

// ============ gather + AB(layer0) + init mi/c0/c1 ===========================
__global__ __launch_bounds__(256) void k_gab(
    const float* __restrict__ feat, const float* __restrict__ coor,
    const float* __restrict__ svals, const int* __restrict__ sidx,
    const float* __restrict__ We1, const float* __restrict__ be1,
    float* __restrict__ hc, float* __restrict__ c0, float* __restrict__ c1,
    float* __restrict__ mi, float* __restrict__ Ap, float* __restrict__ BF){
    int t = threadIdx.x; int u = blockIdx.x*4 + (t>>6); if (u >= KT) return;
    int lane = t&63;
    int l = (u<K0)?0:(u<O2)?1:2;
    int a = u - ((l==0)?0:(l==1)?O1:O2);
    int org = sidx[l*NN+a];
    float val = svals[l*NN+a];
    float hval = feat[org*DIMF+lane]*val;
    hc[u*DIMF+lane] = hval;
    if (lane < 3){ float c = coor[org*3+lane]; c0[u*4+lane]=c; c1[u*4+lane]=c; }
    if (lane == 3){ c0[u*4+3]=0.0f; c1[u*4+3]=0.0f; }
    if (lane < 20) mi[u*20+lane] = 0.0f;
    ab_comp(0, We1, be1, hval, u, lane, Ap, BF);
}

// ============ per-pair edge MLP via MFMA =====================================
// wave = (receiver u, 64-sender tile): two 32-pair MFMA acc sets.
// 1-term RNE: acc = RNE_bf16(s) @ bf16RNE(We2) — both quantizations unbiased
// 2^-9 relative; error budget per R12/R14 measurements. Single v_cvt_pk_bf16
// replaces the 6-inst truncation-split pack; 2 MFMAs per c-iter (was 4).
// Rotating-register pipeline (R9-proven no-spill); (256,4) PROVEN optimum.
template<int DOCW>
__global__ __launch_bounds__(256, 4) void k_pair(
    int jl,
    const float* __restrict__ Ap, const float* __restrict__ BF,
    const u16* __restrict__ W2f, const u16* __restrict__ Wc1f,
    const float* __restrict__ wdP, const float* __restrict__ weP,
    const float* __restrict__ be2P, const float* __restrict__ bc1P,
    const float* __restrict__ Wc2P, const float* __restrict__ bc2,
    const float* __restrict__ cin, float* __restrict__ cout,
    float* __restrict__ mi, const int* __restrict__ sidx,
    const u64* __restrict__ ug2w){
    __shared__ __align__(16) char sWK[4*WVLDS];
    __shared__ __align__(16) char sWD[1088];
    __shared__ __align__(16) char sWE[1088];
    int t = threadIdx.x;
    if (t < 68)       ((float4*)sWD)[t]    = *(const float4*)(wdP + jl*KPAD + 4*t);
    else if (t < 136) ((float4*)sWE)[t-68] = *(const float4*)(weP + jl*KPAD + 4*(t-68));
    int wid0 = blockIdx.x*4 + (t>>6);
    int lane = t&63, n = lane&31, q = lane>>5;
    bool dead = (wid0 >= TTOT);
    int wid = dead ? (TTOT-1) : wid0;
    int l, kl, off, a, tile;
    if (wid < T0T)       { l=0; kl=K0; off=0;  a = wid>>3; tile = wid&7; }
    else if (wid < T01T) { int w = wid-T0T;  l=1; kl=K1; off=O1; a = w/NT1; tile = w - a*NT1; }
    else                 { int w = wid-T01T; l=2; kl=K2; off=O2; a = w/NT2; tile = w - a*NT2; }
    int u = off + a;
    int b0 = tile*64 + n, b1 = b0 + 32;
    float act0 = (b0 < kl) ? 1.0f : 0.0f;
    float act1 = (b1 < kl) ? 1.0f : 0.0f;
    int b0c = min(b0, kl-1), b1c = min(b1, kl-1);
    int ub0 = off + b0c, ub1 = off + b1c;
    int ia  = sidx[l*NN+a];
    int ib0 = sidx[l*NN+b0c], ib1 = sidx[l*NN+b1c];
    float ef0 = act0 * (float)((ug2w[ia*8 + (ib0>>6)] >> (ib0&63)) & 1ULL);
    float ef1 = act1 * (float)((ug2w[ia*8 + (ib1>>6)] >> (ib1&63)) & 1ULL);
    F4U ca;  ca.v  = ((const float4*)cin)[u];
    F4U cb0; cb0.v = ((const float4*)cin)[ub0];
    F4U cb1; cb1.v = ((const float4*)cin)[ub1];
    float tx0 = ca.f[0]-cb0.f[0], ty0 = ca.f[1]-cb0.f[1], tz0 = ca.f[2]-cb0.f[2];
    float tx1 = ca.f[0]-cb1.f[0], ty1 = ca.f[1]-cb1.f[1], tz1 = ca.f[2]-cb1.f[2];
    float dd0 = tx0*tx0 + ty0*ty0 + tz0*tz0;
    float dd1 = tx1*tx1 + ty1*ty1 + tz1*tz1;

    char* myk = sWK + (t>>6)*WVLDS;
    {   // stage A for this wave's receiver
        const float* Au = Ap + u*AS;
        ((float4*)myk)[lane] = *(const float4*)(Au + 4*lane);
        if (lane < 4) ((float4*)myk)[64+lane] = *(const float4*)(Au + 256 + 4*lane);
    }
    __syncthreads();

    const float* pB0 = BF + ((size_t)q*PADU + ub0)*8;
    const float* pB1 = BF + ((size_t)q*PADU + ub1)*8;
    const u16*   pW  = W2f + jl*17408 + lane*8;
    const char*  pA  = myk + q*32;
    const char*  pWD = sWD + q*32;
    const char*  pWE = sWE + q*32;

    f32x16 acc0, acc1;
#pragma unroll
    for (int r = 0; r < 16; r++){ acc0[r] = 0.0f; acc1[r] = 0.0f; }

    // prologue loads for c=0 (rotating pipeline, R9 structure)
    F4U nb0a, nb0b, nb1a, nb1b; SF nwh;
    nb0a.v = *(const float4*)(pB0);     nb0b.v = *(const float4*)(pB0 + 4);
    nb1a.v = *(const float4*)(pB1);     nb1b.v = *(const float4*)(pB1 + 4);
    nwh.i4 = *(const int4*)(pW);

    float2 DD0{dd0,dd0}, EF0{ef0,ef0}, DD1{dd1,dd1}, EF1{ef1,ef1};

    for (int c = 0; c < 17; c++){
        F4U b0a = nb0a, b0b = nb0b, b1a = nb1a, b1b = nb1b;
        SF  wh  = nwh;
        pB0 += 2*PADU*8; pB1 += 2*PADU*8; pW += 1024;
        if (c < 16){   // issue c+1's global loads before computing c
            nb0a.v = *(const float4*)(pB0);     nb0b.v = *(const float4*)(pB0 + 4);
            nb1a.v = *(const float4*)(pB1);     nb1b.v = *(const float4*)(pB1 + 4);
            nwh.i4 = *(const int4*)(pW);
        }
        F4U a0, a1, w0, w1, e0, e1;
        a0.v = *(const float4*)(pA);       a1.v = *(const float4*)(pA + 16);
        w0.v = *(const float4*)(pWD);      w1.v = *(const float4*)(pWD + 16);
        e0.v = *(const float4*)(pWE);      e1.v = *(const float4*)(pWE + 16);
        pA += 64; pWD += 64; pWE += 64;

        SF shi0, shi1;
#pragma unroll
        for (int h = 0; h < 2; h++){
            float2 p00 = f2fma(EF0, e0.h[h], f2fma(DD0, w0.h[h], f2add(a0.h[h], b0a.h[h])));
            float2 p01 = f2fma(EF0, e1.h[h], f2fma(DD0, w1.h[h], f2add(a1.h[h], b0b.h[h])));
            float2 p10 = f2fma(EF1, e0.h[h], f2fma(DD1, w0.h[h], f2add(a0.h[h], b1a.h[h])));
            float2 p11 = f2fma(EF1, e1.h[h], f2fma(DD1, w1.h[h], f2add(a1.h[h], b1b.h[h])));
            float2 s00 = silu2(p00), s01 = silu2(p01);
            float2 s10 = silu2(p10), s11 = silu2(p11);
            shi0.w[h]   = pk_bf16(s00.x, s00.y);
            shi0.w[2+h] = pk_bf16(s01.x, s01.y);
            shi1.w[h]   = pk_bf16(s10.x, s10.y);
            shi1.w[2+h] = pk_bf16(s11.x, s11.y);
        }
        acc0 = __builtin_amdgcn_mfma_f32_32x32x16_bf16(shi0.v, wh.v, acc0, 0, 0, 0);
        acc1 = __builtin_amdgcn_mfma_f32_32x32x16_bf16(shi1.v, wh.v, acc1, 0, 0, 0);
    }

    // ---- m = silu(acc + be2); masked m_i sum; (DOCW) repack to LDS bf16
    float be2v = be2P[jl*32 + n];
    u16* mlds = (u16*)myk;               // overwrites A stage (done with it)
    float msum = 0.0f;
#pragma unroll
    for (int r = 0; r < 16; r++){
        int row = (r&3) + 8*(r>>2) + 4*q;
        float m0 = siluf(acc0[r] + be2v);
        float m1 = siluf(acc1[r] + be2v);
        m0 = (tile*64 + row      < kl) ? m0 : 0.0f;
        m1 = (tile*64 + 32 + row < kl) ? m1 : 0.0f;
        msum += m0 + m1;
        if (DOCW){
            mlds[row*MSTR + n]        = bf16_rne(m0);
            mlds[(row+32)*MSTR + n]   = bf16_rne(m1);
        }
    }
    msum += __shfl_xor(msum, 32);
    if (!dead && lane < MD) atomicAdd(&mi[u*20 + lane], msum);

    if (DOCW){
        lgkm_wait();
        const char* mb = (const char*)mlds;
        float gx = 0.0f, gy = 0.0f, gz = 0.0f;
        float bc2v = bc2[jl];
#pragma unroll
        for (int S = 0; S < 2; S++){
            SF af0, af1;
            af0.i4 = *(const int4*)(mb + (S*32+n)*(MSTR*2) + q*16);
            af1.i4 = *(const int4*)(mb + (S*32+n)*(MSTR*2) + 32 + q*16);
            float cwp[16];
#pragma unroll
            for (int r = 0; r < 16; r++) cwp[r] = 0.0f;
            for (int T = 0; T < 3; T++){
                SF bb0, bb1;
                bb0.i4 = *(const int4*)(Wc1f + jl*3072 + T*1024 +       lane*8);
                bb1.i4 = *(const int4*)(Wc1f + jl*3072 + T*1024 + 512 + lane*8);
                f32x16 p2;
#pragma unroll
                for (int r = 0; r < 16; r++) p2[r] = 0.0f;
                p2 = __builtin_amdgcn_mfma_f32_32x32x16_bf16(af0.v, bb0.v, p2, 0, 0, 0);
                p2 = __builtin_amdgcn_mfma_f32_32x32x16_bf16(af1.v, bb1.v, p2, 0, 0, 0);
                float bc1v = bc1P[jl*96 + T*32 + n];
                float wc2v = Wc2P[jl*96 + T*32 + n];
#pragma unroll
                for (int r = 0; r < 16; r++)
                    cwp[r] = fmaf(siluf(p2[r] + bc1v), wc2v, cwp[r]);
            }
#pragma unroll
            for (int r = 0; r < 16; r++){
                int row  = (r&3) + 8*(r>>2) + 4*q + S*32;
                int brow = tile*64 + row;
                F4U cbr; cbr.v = ((const float4*)cin)[off + min(brow, kl-1)];
                float cw = cwp[r] + ((n == 0) ? bc2v : 0.0f);
                cw = (brow < kl) ? cw : 0.0f;
                gx = fmaf(cw, ca.f[0]-cbr.f[0], gx);
                gy = fmaf(cw, ca.f[1]-cbr.f[1], gy);
                gz = fmaf(cw, ca.f[2]-cbr.f[2], gz);
            }
        }
#pragma unroll
        for (int s = 1; s < 64; s <<= 1){
            gx += __shfl_xor(gx, s); gy += __shfl_xor(gy, s); gz += __shfl_xor(gz, s);
        }
        if (!dead && lane == 0){
            atomicAdd(&cout[u*4+0], gx);
            atomicAdd(&cout[u*4+1], gy);
            atomicAdd(&cout[u*4+2], gz);
        }
    }
}

// ============ node MLP + (optionally) AB for next layer + inits ==============
__global__ __launch_bounds__(256) void k_nodeab(
    int jl, int donext, int docopy,
    const float* __restrict__ Wn1, const float* __restrict__ bn1,
    const float* __restrict__ Wn2, const float* __restrict__ bn2,
    const float* __restrict__ We1, const float* __restrict__ be1,
    float* __restrict__ hc, float* __restrict__ mi,
    const float* __restrict__ ccur, float* __restrict__ cnext,
    float* __restrict__ Ap, float* __restrict__ BF){
    int t = threadIdx.x; int u = blockIdx.x*4 + (t>>6); if (u >= KT) return;
    int lane = t&63;
    float hval = hc[u*DIMF+lane];
    float mval = (lane < MD) ? mi[u*20+lane] : 0.0f;
    const float* W1 = Wn1 + jl*(DIMF+MD)*NH1;
    float v0 = bn1[jl*NH1+lane], v1 = bn1[jl*NH1+lane+64];
    for (int d = 0; d < DIMF; d++){
        float x = __shfl(hval, d);
        v0 = fmaf(x, W1[d*NH1+lane],    v0);
        v1 = fmaf(x, W1[d*NH1+lane+64], v1);
    }
    for (int d = 0; d < MD; d++){
        float x = __shfl(mval, d);
        v0 = fmaf(x, W1[(DIMF+d)*NH1+lane],    v0);
        v1 = fmaf(x, W1[(DIMF+d)*NH1+lane+64], v1);
    }
    float s0 = siluf(v0), s1 = siluf(v1);
    const float* W2 = Wn2 + jl*NH1*DIMF;
    float h = bn2[jl*DIMF+lane];
    for (int i = 0; i < 64; i++) h = fmaf(__shfl(s0, i), W2[i*DIMF+lane], h);
    for (int i = 0; i < 64; i++) h = fmaf(__shfl(s1, i), W2[(64+i)*DIMF+lane], h);
    float hn = fmaxf(0.0f, fmaf(2.0f, hval, h));
    hc[u*DIMF+lane] = hn;
    if (donext){
        if (lane < 20) mi[u*20+lane] = 0.0f;
        if (docopy && lane < 4) cnext[u*4+lane] = ccur[u*4+lane];
        ab_comp(jl+1, We1, be1, hn, u, lane, Ap, BF);
    }
}

// ============ scatter + 3-level max =========================================
__global__ void k_final(const float* __restrict__ hc, const int* __restrict__ rev,
                        float* __restrict__ out){
    int gid = blockIdx.x*blockDim.x + threadIdx.x;
    if (gid >= NN*DIMF) return;
    int nn = gid>>6, d = gid&63;
    float v = 0.0f;
    int a0 = rev[0*NN+nn]; if (a0 >= 0) v = fmaxf(v, hc[(0  + a0)*DIMF + d]);
    int a1 = rev[1*NN+nn]; if (a1 >= 0) v = fmaxf(v, hc[(O1 + a1)*DIMF + d]);
    int a2 = rev[2*NN+nn]; if (a2 >= 0) v = fmaxf(v, hc[(O2 + a2)*DIMF + d]);
    out[gid] = v;
}

extern "C" void kernel_launch(void* const* d_in, const int* in_sizes, int n_in,
                              void* d_out, int out_size, void* d_ws, size_t ws_size,
                              hipStream_t stream) {
    (void)in_sizes; (void)n_in; (void)out_size; (void)ws_size;
    const float* feat = (const float*)d_in[0];
    const float* coor = (const float*)d_in[1];
    const float* edge = (const float*)d_in[2];
    const float* We1  = (const float*)d_in[3];
    const float* be1  = (const float*)d_in[4];
    const float* We2  = (const float*)d_in[5];
    const float* be2  = (const float*)d_in[6];
    const float* Wc1  = (const float*)d_in[7];
    const float* bc1  = (const float*)d_in[8];
    const float* Wc2  = (const float*)d_in[9];
    const float* bc2  = (const float*)d_in[10];
    const float* Wn1  = (const float*)d_in[11];
    const float* bn1  = (const float*)d_in[12];
    const float* Wn2  = (const float*)d_in[13];
    const float* bn2  = (const float*)d_in[14];
    const float* wp   = (const float*)d_in[15];
    const float* bp   = (const float*)d_in[16];
    float* out = (float*)d_out;

    char* wsb = (char*)d_ws;
    u64*   ugw    = (u64*)  (wsb + 0);         // 32768
    u64*   ug2w   = (u64*)  (wsb + 32768);     // 32768
    float* scores = (float*)(wsb + 65536);     // 6144
    float* svals  = (float*)(wsb + 71680);     // 6144
    int*   sidx   = (int*)  (wsb + 77824);     // 6144
    int*   rev    = (int*)  (wsb + 83968);     // 6144
    float* c0     = (float*)(wsb + 90112);     // 18432
    float* c1     = (float*)(wsb + 108544);    // 18432
    float* mi     = (float*)(wsb + 126976);    // 90112
    float* hc     = (float*)(wsb + 217088);    // 288256
    float* Ap     = (float*)(wsb + 505344);    // 1224192
    float* BF     = (float*)(wsb + 1729536);   // 1253376 (34*1152*8*4)
    u16*   W2f    = (u16*)  (wsb + 2982912);   // 104448  (3*17*2*512*2)
    u16*   Wc1f   = (u16*)  (wsb + 3087360);   // 18432
    float* wdP    = (float*)(wsb + 3105792);   // 3328
    float* weP    = (float*)(wsb + 3109120);   // 3328
    float* be2P   = (float*)(wsb + 3112448);   // 384
    float* bc1P   = (float*)(wsb + 3112832);   // 1152
    float* Wc2P   = (float*)(wsb + 3113984);   // 1152  (end ~3.12 MB)

    k_pre<<<399, 256, 0, stream>>>(edge, feat, wp, bp, We2, Wc1, We1, be2, bc1, Wc2,
                                   ugw, scores, W2f, Wc1f,
                                   wdP, weP, be2P, bc1P, Wc2P, ug2w);
    k_sortug2<<<67, 512, 0, stream>>>(scores, ugw, svals, sidx, rev, ug2w);
    k_gab<<<282, 256, 0, stream>>>(feat, coor, svals, sidx, We1, be1,
                                   hc, c0, c1, mi, Ap, BF);
    // layer 0: cin=c0, cout=c1
    k_pair<1><<<PBLK, 256, 0, stream>>>(0, Ap, BF, W2f, Wc1f,
                                        wdP, weP, be2P, bc1P, Wc2P, bc2,
                                        c0, c1, mi, sidx, ug2w);
    k_nodeab<<<282, 256, 0, stream>>>(0, 1, 1, Wn1, bn1, Wn2, bn2, We1, be1,
                                      hc, mi, c1, c0, Ap, BF);
    // layer 1: cin=c1, cout=c0 (pre-initialized to c1 by k_nodeab)
    k_pair<1><<<PBLK, 256, 0, stream>>>(1, Ap, BF, W2f, Wc1f,
                                        wdP, weP, be2P, bc1P, Wc2P, bc2,
                                        c1, c0, mi, sidx, ug2w);
    k_nodeab<<<282, 256, 0, stream>>>(1, 1, 0, Wn1, bn1, Wn2, bn2, We1, be1,
                                      hc, mi, c0, c1, Ap, BF);
    // layer 2: coords output unused -> no coord MLP instantiation
    k_pair<0><<<PBLK, 256, 0, stream>>>(2, Ap, BF, W2f, Wc1f,
                                        wdP, weP, be2P, bc1P, Wc2P, bc2,
                                        c0, c1, mi, sidx, ug2w);
    k_nodeab<<<282, 256, 0, stream>>>(2, 0, 0, Wn1, bn1, Wn2, bn2, We1, be1,
                                      hc, mi, c0, c1, Ap, BF);
    k_final<<<128, 256, 0, stream>>>(hc, rev, out);
}